// Round 16
// baseline (97.319 us; speedup 1.0000x reference)
//
#include <hip/hip_runtime.h>
#include <hip/hip_bf16.h>
#include <stdint.h>

#define NN   50000
#define NE   800000
#define INF_ 16
#define OUTF 32
#define HIDN 25
#define NC   10
#define QG   2048                 // edge_attr quantization levels
#define QPB  16                   // q values per prep_G block
#define DPB  8                    // dsts per bucket
#define NB   6250                 // 50000/8
#define EPB  4096                 // edges per sort block
#define NBLK 196                  // ceil(NE/EPB)
#define ASTR 33                   // padded agg row stride
#define ECAP 384                  // LDS-staged edges per bucket (mean 128)
#define SCH  25                   // ceil(NB/256) for binscan

#define SENT 0x007FFFFFu          // map_f(-inf)

#define GB_PREP 128               // prep_G blocks
#define GB_HIST NBLK              // hist blocks
#define GB_XH   391               // ceil(NN*INF_/2/1024), 4 pairs/thread

typedef _Float16 f16x2 __attribute__((ext_vector_type(2)));

__device__ __forceinline__ uint32_t map_f(float f) {
    uint32_t b = __float_as_uint(f);
    return (b & 0x80000000u) ? ~b : (b | 0x80000000u);
}
__device__ __forceinline__ float unmap_f(uint32_t u) {
    return (u & 0x80000000u) ? __uint_as_float(u ^ 0x80000000u)
                             : __uint_as_float(~u);
}

__device__ __forceinline__ float dot2f(uint32_t g, uint32_t xb, float acc) {
#if __has_builtin(__builtin_amdgcn_fdot2)
    union { uint32_t u; f16x2 h; } ug, ux;
    ug.u = g; ux.u = xb;
    return __builtin_amdgcn_fdot2(ug.h, ux.h, acc, false);
#else
    union { uint32_t u; _Float16 h[2]; } ug, ux;
    ug.u = g; ux.u = xb;
    return fmaf((float)ug.h[0], (float)ux.h[0],
                fmaf((float)ug.h[1], (float)ux.h[1], acc));
#endif
}

// ---------- merged prep: [0,128) G2; [128,324) hist H[bin][blk]; rest xh ----------
__global__ __launch_bounds__(256) void prep_k(const float* __restrict__ w1,
                                              const float* __restrict__ b1,
                                              const float* __restrict__ w2,
                                              const float* __restrict__ b2,
                                              const float* __restrict__ x,
                                              const int* __restrict__ ei,
                                              uint32_t* __restrict__ G2,
                                              uint32_t* __restrict__ xh,
                                              uint32_t* __restrict__ H) {
    __shared__ union {
        struct { float w2s[HIDN * 512]; float b2s[512]; float hs[QPB][HIDN]; } g;
        uint32_t hloc[NB];
    } sm;

    const int b = blockIdx.x;
    if (b < GB_PREP) {
        for (int i = threadIdx.x; i < HIDN * 512; i += 256) sm.g.w2s[i] = w2[i];
        for (int i = threadIdx.x; i < 512; i += 256) sm.g.b2s[i] = b2[i];
        for (int i = threadIdx.x; i < QPB * HIDN; i += 256) {
            int qq = i / HIDN, k = i - qq * HIDN;
            float aq = (b * QPB + qq + 0.5f) * (1.0f / (float)QG);
            sm.g.hs[qq][k] = fmaxf(fmaf(aq, w1[k], b1[k]), 0.f);
        }
        __syncthreads();
        for (int qq = 0; qq < QPB; ++qq) {
            const int q = b * QPB + qq;
            int e = threadIdx.x;
            int ip = e >> 5, o = e & 31;
            float g0 = sm.g.b2s[(2 * ip) * OUTF + o];
            float g1 = sm.g.b2s[(2 * ip + 1) * OUTF + o];
#pragma unroll
            for (int k = 0; k < HIDN; ++k) {
                float h = sm.g.hs[qq][k];
                g0 = fmaf(h, sm.g.w2s[k * 512 + (2 * ip) * OUTF + o], g0);
                g1 = fmaf(h, sm.g.w2s[k * 512 + (2 * ip + 1) * OUTF + o], g1);
            }
            union { uint32_t u; f16x2 h2; } p;
            p.h2[0] = (_Float16)g0;
            p.h2[1] = (_Float16)g1;
            G2[(size_t)q * 256 + e] = p.u;
        }
    } else if (b < GB_PREP + GB_HIST) {
        const int blk = b - GB_PREP;
        for (int i = threadIdx.x; i < NB; i += 256) sm.hloc[i] = 0;
        __syncthreads();
        const int base = blk * EPB;
        for (int j = 0; j < EPB; j += 256) {
            int e = base + j + threadIdx.x;
            if (e < NE) atomicAdd(&sm.hloc[ei[NE + e] >> 3], 1u);
        }
        __syncthreads();
        for (int i = threadIdx.x; i < NB; i += 256)
            H[(size_t)i * NBLK + blk] = sm.hloc[i];
    } else {
        // x -> packed f16 pairs, 4 pairs (8 floats) per thread
        int t4 = ((b - GB_PREP - GB_HIST) * 256 + threadIdx.x) * 4;
        if (t4 < NN * INF_ / 2) {
            const float4* xp = reinterpret_cast<const float4*>(x) + (t4 >> 1);
            float4 va = xp[0];
            float4 vb = xp[1];
            union { uint32_t u[4]; f16x2 h[4]; } p;
            p.h[0][0] = (_Float16)va.x; p.h[0][1] = (_Float16)va.y;
            p.h[1][0] = (_Float16)va.z; p.h[1][1] = (_Float16)va.w;
            p.h[2][0] = (_Float16)vb.x; p.h[2][1] = (_Float16)vb.y;
            p.h[3][0] = (_Float16)vb.z; p.h[3][1] = (_Float16)vb.w;
            *reinterpret_cast<uint4*>(xh + t4) = make_uint4(p.u[0], p.u[1], p.u[2], p.u[3]);
        }
    }
}

// ---------- wave per bin: exclusive prefix over blocks via shfl scan ----------
__global__ __launch_bounds__(256) void colsum_k(const uint32_t* __restrict__ H,
                                                uint32_t* __restrict__ Bp,
                                                uint32_t* __restrict__ tot) {
    const int bin  = (blockIdx.x * 256 + threadIdx.x) >> 6;
    const int lane = threadIdx.x & 63;
    if (bin >= NB) return;
    const uint32_t* hr = H + (size_t)bin * NBLK;
    uint32_t* br = Bp + (size_t)bin * NBLK;
    uint32_t carry = 0;
    for (int b0 = 0; b0 < NBLK; b0 += 64) {
        int b = b0 + lane;
        uint32_t v = (b < NBLK) ? hr[b] : 0;
        uint32_t inc = v;
#pragma unroll
        for (int off = 1; off < 64; off <<= 1) {
            uint32_t t = __shfl_up(inc, off);
            if (lane >= off) inc += t;
        }
        if (b < NBLK) br[b] = carry + inc - v;
        carry += __shfl(inc, 63);
    }
    if (lane == 0) tot[bin] = carry;
}

// ---------- exclusive scan of NB bucket totals (single block, chunked) ----------
__global__ __launch_bounds__(256) void binscan_k(const uint32_t* __restrict__ tot,
                                                 uint32_t* __restrict__ bstart) {
    __shared__ uint32_t part[256];
    const int t = threadIdx.x;
    uint32_t loc[SCH];
    uint32_t s = 0;
#pragma unroll
    for (int j = 0; j < SCH; ++j) {
        int idx = t * SCH + j;
        uint32_t v = (idx < NB) ? tot[idx] : 0;
        loc[j] = s;
        s += v;
    }
    part[t] = s;
    __syncthreads();
    for (int off = 1; off < 256; off <<= 1) {
        uint32_t add = (t >= off) ? part[t - off] : 0;
        __syncthreads();
        part[t] += add;
        __syncthreads();
    }
    uint32_t base = (t > 0) ? part[t - 1] : 0;
#pragma unroll
    for (int j = 0; j < SCH; ++j) {
        int idx = t * SCH + j;
        if (idx < NB) bstart[idx] = base + loc[j];
    }
    if (t == 255) bstart[NB] = part[255];
}

// ---------- scatter: small-LDS, Bp/bstart via L2; pack (q11|src16|db5) ----------
__global__ __launch_bounds__(256) void scatter_k(const int* __restrict__ ei,
                                                 const float* __restrict__ ea,
                                                 const uint32_t* __restrict__ Bp,
                                                 const uint32_t* __restrict__ bstart,
                                                 uint32_t* __restrict__ sorted) {
    __shared__ uint32_t cur[NB];                 // 25 KB; scatter has only 196 blocks
    for (int i = threadIdx.x; i < NB; i += 256) cur[i] = 0;
    __syncthreads();
    const int base = blockIdx.x * EPB;
    for (int j = 0; j < EPB; j += 256) {
        int e = base + j + threadIdx.x;
        if (e < NE) {
            int sn = ei[e];
            int d  = ei[NE + e];
            float a = ea[e];
            int q = (int)(a * (float)QG);
            q = q < 0 ? 0 : (q > QG - 1 ? QG - 1 : q);
            int bin = d >> 3;
            uint32_t r = atomicAdd(&cur[bin], 1u);
            uint32_t pos = bstart[bin] + Bp[(size_t)bin * NBLK + blockIdx.x] + r;
            sorted[pos] = ((uint32_t)q << 21) | ((uint32_t)sn << 5)
                        | (uint32_t)(d & 7);
        }
    }
}

// ---------- fused: 8 lanes/edge, dot2, unroll-2, LDS max-agg, epilogue ----------
__global__ __launch_bounds__(256) void fused_k(const uint32_t* __restrict__ sorted,
                                               const uint32_t* __restrict__ bstart,
                                               const float* __restrict__ x,
                                               const uint32_t* __restrict__ xh,
                                               const uint32_t* __restrict__ G2,
                                               const float* __restrict__ root,
                                               const float* __restrict__ bias,
                                               const float* __restrict__ fcw,
                                               const float* __restrict__ fcb,
                                               float* __restrict__ out) {
    __shared__ uint32_t ebuf[ECAP];              // 1.5 KB staged edge records
    __shared__ uint32_t agg[DPB * ASTR];         // 1.06 KB
    __shared__ float rs[INF_ * OUTF];
    __shared__ float bs[OUTF];
    __shared__ float fws[OUTF * NC];
    __shared__ float fbs[NC];

    const int bin  = blockIdx.x;
    const int segs = (int)bstart[bin];
    const int cnt  = (int)bstart[bin + 1] - segs;
    const int scnt = cnt < ECAP ? cnt : ECAP;

    for (int i = threadIdx.x; i < scnt; i += 256) ebuf[i] = sorted[segs + i];
    for (int i = threadIdx.x; i < DPB * ASTR; i += 256) agg[i] = SENT;
    for (int i = threadIdx.x; i < INF_ * OUTF; i += 256) rs[i] = root[i];
    if (threadIdx.x < OUTF) bs[threadIdx.x] = bias[threadIdx.x];
    for (int i = threadIdx.x; i < OUTF * NC; i += 256) fws[i] = fcw[i];
    if (threadIdx.x < NC) fbs[threadIdx.x] = fcb[threadIdx.x];
    __syncthreads();

    const int c   = threadIdx.x & 7;             // owns channels 4c..4c+3
    const int grp = threadIdx.x >> 3;            // 0..31 edge groups

#define EDGE_LOAD(rec, hx0, hx1, gq)                                            \
    int src_ = ((rec) >> 5) & 0xFFFF;                                           \
    int q_ = (rec) >> 21;                                                       \
    const uint4* xp_ = reinterpret_cast<const uint4*>(xh) + src_ * 2;           \
    hx0 = xp_[0]; hx1 = xp_[1];                                                 \
    gq = reinterpret_cast<const uint4*>(G2) + (size_t)q_ * 64 + c;

#define EDGE_DOT(hx0, hx1, gq, p0, p1, p2, p3)                                  \
    {                                                                           \
        uint4 g0 = gq[0],  g1 = gq[8],  g2 = gq[16], g3 = gq[24];               \
        uint4 g4 = gq[32], g5 = gq[40], g6 = gq[48], g7 = gq[56];               \
        p0 = dot2f(g0.x, hx0.x, p0); p1 = dot2f(g0.y, hx0.x, p1);               \
        p2 = dot2f(g0.z, hx0.x, p2); p3 = dot2f(g0.w, hx0.x, p3);               \
        p0 = dot2f(g1.x, hx0.y, p0); p1 = dot2f(g1.y, hx0.y, p1);               \
        p2 = dot2f(g1.z, hx0.y, p2); p3 = dot2f(g1.w, hx0.y, p3);               \
        p0 = dot2f(g2.x, hx0.z, p0); p1 = dot2f(g2.y, hx0.z, p1);               \
        p2 = dot2f(g2.z, hx0.z, p2); p3 = dot2f(g2.w, hx0.z, p3);               \
        p0 = dot2f(g3.x, hx0.w, p0); p1 = dot2f(g3.y, hx0.w, p1);               \
        p2 = dot2f(g3.z, hx0.w, p2); p3 = dot2f(g3.w, hx0.w, p3);               \
        p0 = dot2f(g4.x, hx1.x, p0); p1 = dot2f(g4.y, hx1.x, p1);               \
        p2 = dot2f(g4.z, hx1.x, p2); p3 = dot2f(g4.w, hx1.x, p3);               \
        p0 = dot2f(g5.x, hx1.y, p0); p1 = dot2f(g5.y, hx1.y, p1);               \
        p2 = dot2f(g5.z, hx1.y, p2); p3 = dot2f(g5.w, hx1.y, p3);               \
        p0 = dot2f(g6.x, hx1.z, p0); p1 = dot2f(g6.y, hx1.z, p1);               \
        p2 = dot2f(g6.z, hx1.z, p2); p3 = dot2f(g6.w, hx1.z, p3);               \
        p0 = dot2f(g7.x, hx1.w, p0); p1 = dot2f(g7.y, hx1.w, p1);               \
        p2 = dot2f(g7.z, hx1.w, p2); p3 = dot2f(g7.w, hx1.w, p3);               \
    }

    int it = grp;
    for (; it + 32 < cnt; it += 64) {
        uint32_t recA = (it < ECAP) ? ebuf[it] : sorted[segs + it];
        int itB = it + 32;
        uint32_t recB = (itB < ECAP) ? ebuf[itB] : sorted[segs + itB];
        uint4 ax0, ax1, bx0, bx1;
        const uint4 *gqA, *gqB;
        { EDGE_LOAD(recA, ax0, ax1, gqA) }
        int dbA = recA & 7;
        { EDGE_LOAD(recB, bx0, bx1, gqB) }
        int dbB = recB & 7;

        float a0 = 0.f, a1 = 0.f, a2 = 0.f, a3 = 0.f;
        float b0 = 0.f, b1 = 0.f, b2 = 0.f, b3 = 0.f;
        EDGE_DOT(ax0, ax1, gqA, a0, a1, a2, a3)
        EDGE_DOT(bx0, bx1, gqB, b0, b1, b2, b3)

        uint32_t* agA = &agg[dbA * ASTR + c * 4];
        atomicMax(&agA[0], map_f(a0));
        atomicMax(&agA[1], map_f(a1));
        atomicMax(&agA[2], map_f(a2));
        atomicMax(&agA[3], map_f(a3));
        uint32_t* agB = &agg[dbB * ASTR + c * 4];
        atomicMax(&agB[0], map_f(b0));
        atomicMax(&agB[1], map_f(b1));
        atomicMax(&agB[2], map_f(b2));
        atomicMax(&agB[3], map_f(b3));
    }
    if (it < cnt) {
        uint32_t recA = (it < ECAP) ? ebuf[it] : sorted[segs + it];
        uint4 ax0, ax1;
        const uint4* gqA;
        { EDGE_LOAD(recA, ax0, ax1, gqA) }
        int dbA = recA & 7;
        float a0 = 0.f, a1 = 0.f, a2 = 0.f, a3 = 0.f;
        EDGE_DOT(ax0, ax1, gqA, a0, a1, a2, a3)
        uint32_t* agA = &agg[dbA * ASTR + c * 4];
        atomicMax(&agA[0], map_f(a0));
        atomicMax(&agA[1], map_f(a1));
        atomicMax(&agA[2], map_f(a2));
        atomicMax(&agA[3], map_f(a3));
    }
    __syncthreads();

    // epilogue: 8 dsts x (8 lanes x 4 channels); first 64 threads
    {
        const int li8 = threadIdx.x & 7;
        const int dl  = threadIdx.x >> 3;
        const int n   = bin * DPB + dl;
        if (dl < DPB && n < NN) {
            const uint32_t* ar = &agg[dl * ASTR + li8 * 4];
            float av[4];
#pragma unroll
            for (int qq = 0; qq < 4; ++qq) {
                uint32_t u = ar[qq];
                av[qq] = (u == SENT) ? 0.f : unmap_f(u);
            }
            const float* xr = x + (size_t)n * INF_;
            float4 xa = *reinterpret_cast<const float4*>(xr);
            float4 xb = *reinterpret_cast<const float4*>(xr + 4);
            float4 xc = *reinterpret_cast<const float4*>(xr + 8);
            float4 xd = *reinterpret_cast<const float4*>(xr + 12);
            float xv[INF_] = {xa.x,xa.y,xa.z,xa.w, xb.x,xb.y,xb.z,xb.w,
                              xc.x,xc.y,xc.z,xc.w, xd.x,xd.y,xd.z,xd.w};
            float ov[4];
#pragma unroll
            for (int qq = 0; qq < 4; ++qq) {
                int oc = li8 * 4 + qq;
                float tv = av[qq] + bs[oc];
#pragma unroll
                for (int i = 0; i < INF_; ++i) tv = fmaf(xv[i], rs[i * OUTF + oc], tv);
                ov[qq] = (tv > 0.f) ? tv : expm1f(tv);   // ELU alpha=1
            }
            float lg[NC];
#pragma unroll
            for (int cc = 0; cc < NC; ++cc) {
                float tv = 0.f;
#pragma unroll
                for (int qq = 0; qq < 4; ++qq) tv = fmaf(ov[qq], fws[(li8 * 4 + qq) * NC + cc], tv);
                lg[cc] = tv;
            }
#pragma unroll
            for (int m = 1; m <= 4; m <<= 1) {
#pragma unroll
                for (int cc = 0; cc < NC; ++cc) lg[cc] += __shfl_xor(lg[cc], m);
            }
#pragma unroll
            for (int cc = 0; cc < NC; ++cc) lg[cc] += fbs[cc];

            float mx = lg[0];
#pragma unroll
            for (int cc = 1; cc < NC; ++cc) mx = fmaxf(mx, lg[cc]);
            float ssum = 0.f;
#pragma unroll
            for (int cc = 0; cc < NC; ++cc) ssum += expf(lg[cc] - mx);
            float lse = mx + logf(ssum);

            float* orow = out + (size_t)n * NC;
            orow[li8] = lg[li8] - lse;
            if (li8 < 2) orow[8 + li8] = lg[8 + li8] - lse;
        }
    }
}

extern "C" void kernel_launch(void* const* d_in, const int* in_sizes, int n_in,
                              void* d_out, int out_size, void* d_ws, size_t ws_size,
                              hipStream_t stream) {
    const float* x    = (const float*)d_in[0];
    const float* ea   = (const float*)d_in[1];
    const int*   ei   = (const int*)d_in[2];
    const float* w1   = (const float*)d_in[3];
    const float* b1   = (const float*)d_in[4];
    const float* w2   = (const float*)d_in[5];
    const float* b2   = (const float*)d_in[6];
    const float* root = (const float*)d_in[7];
    const float* bias = (const float*)d_in[8];
    const float* fcw  = (const float*)d_in[9];
    const float* fcb  = (const float*)d_in[10];
    float* out = (float*)d_out;

    size_t off = 0;
    auto alloc = [&](size_t bytes) {
        void* p = (char*)d_ws + off;
        off += (bytes + 255) & ~(size_t)255;
        return p;
    };
    uint32_t* G2       = (uint32_t*)alloc((size_t)QG * 256 * 4);               // 2 MB
    uint32_t* xh       = (uint32_t*)alloc((size_t)NN * INF_ * 2);              // 1.6 MB
    uint32_t* H        = (uint32_t*)alloc((size_t)NB * NBLK * 4);              // 4.9 MB
    uint32_t* Bp       = (uint32_t*)alloc((size_t)NB * NBLK * 4);              // 4.9 MB
    uint32_t* tot      = (uint32_t*)alloc((size_t)NB * 4);
    uint32_t* bstart   = (uint32_t*)alloc((size_t)(NB + 1) * 4);
    uint32_t* sorted   = (uint32_t*)alloc((size_t)NE * 4);                     // 3.2 MB

    prep_k<<<GB_PREP + GB_HIST + GB_XH, 256, 0, stream>>>(w1, b1, w2, b2, x, ei, G2, xh, H);
    colsum_k<<<(NB * 64 + 255) / 256, 256, 0, stream>>>(H, Bp, tot);
    binscan_k<<<1, 256, 0, stream>>>(tot, bstart);
    scatter_k<<<NBLK, 256, 0, stream>>>(ei, ea, Bp, bstart, sorted);
    fused_k<<<NB, 256, 0, stream>>>(sorted, bstart, x, xh, G2, root, bias, fcw, fcb, out);
}

// Round 17
// 86.776 us; speedup vs baseline: 1.1215x; 1.1215x over previous
//
#include <hip/hip_runtime.h>
#include <hip/hip_bf16.h>
#include <stdint.h>

#define NN   50000
#define NE   800000
#define INF_ 16
#define OUTF 32
#define HIDN 25
#define NC   10
#define QG   2048                 // fallback-path quantization levels
#define QPB  16
#define DPB  16                   // dsts per bucket
#define NB   3125                 // 50000/16
#define EPB  4096
#define NBLK 196                  // ceil(NE/EPB)
#define ASTR 33
#define ECAP 768                  // staged edges per bucket (mean 256)
#define SCH  13                   // ceil(NB/256)

#define SENT 0x007FFFFFu          // map_f(-inf)

#define GB_PQ   98                // PQ-prep blocks (512 nodes each)
#define GB_HIST NBLK
#define GB_G2   128               // fallback G2 prep (flag-gated)
#define GB_XH   391               // fallback xh prep (flag-gated)

typedef _Float16 f16x2 __attribute__((ext_vector_type(2)));

__device__ __forceinline__ uint32_t map_f(float f) {
    uint32_t b = __float_as_uint(f);
    return (b & 0x80000000u) ? ~b : (b | 0x80000000u);
}
__device__ __forceinline__ float unmap_f(uint32_t u) {
    return (u & 0x80000000u) ? __uint_as_float(u ^ 0x80000000u)
                             : __uint_as_float(~u);
}
__device__ __forceinline__ float f16lo(uint32_t u) {
    union { uint16_t s; _Float16 h; } v; v.s = (uint16_t)(u & 0xFFFF);
    return (float)v.h;
}
__device__ __forceinline__ float f16hi(uint32_t u) {
    union { uint16_t s; _Float16 h; } v; v.s = (uint16_t)(u >> 16);
    return (float)v.h;
}
__device__ __forceinline__ uint32_t packf16(float a, float b) {
    union { uint32_t u; f16x2 h; } p;
    p.h[0] = (_Float16)a; p.h[1] = (_Float16)b;
    return p.u;
}
__device__ __forceinline__ float dot2f(uint32_t g, uint32_t xb, float acc) {
#if __has_builtin(__builtin_amdgcn_fdot2)
    union { uint32_t u; f16x2 h; } ug, ux;
    ug.u = g; ux.u = xb;
    return __builtin_amdgcn_fdot2(ug.h, ux.h, acc, false);
#else
    return fmaf(f16lo(g), f16lo(xb), fmaf(f16hi(g), f16hi(xb), acc));
#endif
}

// ---------- flag: single-segment detection + active mask ----------
__global__ __launch_bounds__(64) void flag_k(const float* __restrict__ w1,
                                             const float* __restrict__ b1,
                                             uint32_t* __restrict__ flagw) {
    if (threadIdx.x == 0) {
        uint32_t flag = 1, mask = 0;
        for (int k = 0; k < HIDN; ++k) {
            float w = w1[k], b = b1[k];
            if (w != 0.f) {
                float t = -b / w;
                if (t > 0.f && t < 1.f) flag = 0;   // interior breakpoint
            }
            if (fmaf(0.5f, w, b) > 0.f) mask |= (1u << k);  // active on segment
        }
        flagw[0] = flag;
        flagw[1] = mask;
    }
}

// ---------- prep: [0,98) PQ; [98,294) hist; [294,422) G2 (gated); rest xh (gated) ----------
__global__ __launch_bounds__(256) void prep_k(const float* __restrict__ w1,
                                              const float* __restrict__ b1,
                                              const float* __restrict__ w2,
                                              const float* __restrict__ b2,
                                              const float* __restrict__ x,
                                              const int* __restrict__ ei,
                                              const uint32_t* __restrict__ flagw,
                                              uint32_t* __restrict__ PQ,
                                              uint32_t* __restrict__ G2,
                                              uint32_t* __restrict__ xh,
                                              uint32_t* __restrict__ H) {
    __shared__ union {
        struct {
            float w2s[HIDN * 512];
            float b2s[512];
            float ca[512];
            float cb[512];
            float hs[QPB][HIDN];
        } g;
        uint32_t hloc[NB];
    } sm;

    const int b = blockIdx.x;
    if (b < GB_PQ) {
        // ---- P/Q tables: P = x·(b2 + sum_act b1k w2k), Q = x·(sum_act w1k w2k) ----
        for (int i = threadIdx.x; i < HIDN * 512; i += 256) sm.g.w2s[i] = w2[i];
        for (int i = threadIdx.x; i < 512; i += 256) sm.g.b2s[i] = b2[i];
        __syncthreads();
        const uint32_t mask = flagw[1];
        for (int e = threadIdx.x; e < 512; e += 256) {
            float ca = sm.g.b2s[e], cb = 0.f;
            for (int k = 0; k < HIDN; ++k) {
                if ((mask >> k) & 1u) {
                    float wv = sm.g.w2s[k * 512 + e];
                    ca = fmaf(b1[k], wv, ca);
                    cb = fmaf(w1[k], wv, cb);
                }
            }
            sm.g.ca[e] = ca;
            sm.g.cb[e] = cb;
        }
        __syncthreads();
        for (int rep = 0; rep < 2; ++rep) {
            int n = b * 512 + rep * 256 + threadIdx.x;
            if (n < NN) {
                float xv[INF_];
                const float* xr = x + (size_t)n * INF_;
#pragma unroll
                for (int i = 0; i < INF_; i += 4) {
                    float4 v = *reinterpret_cast<const float4*>(xr + i);
                    xv[i] = v.x; xv[i+1] = v.y; xv[i+2] = v.z; xv[i+3] = v.w;
                }
                float P[OUTF], Q[OUTF];
#pragma unroll
                for (int o = 0; o < OUTF; ++o) {
                    float p = 0.f, q = 0.f;
#pragma unroll
                    for (int i = 0; i < INF_; ++i) {
                        p = fmaf(xv[i], sm.g.ca[i * 32 + o], p);
                        q = fmaf(xv[i], sm.g.cb[i * 32 + o], q);
                    }
                    P[o] = p; Q[o] = q;
                }
                uint32_t* row = PQ + (size_t)n * 32;
#pragma unroll
                for (int j = 0; j < 16; ++j) row[j] = packf16(P[2*j], P[2*j+1]);
#pragma unroll
                for (int j = 0; j < 16; ++j) row[16+j] = packf16(Q[2*j], Q[2*j+1]);
            }
        }
    } else if (b < GB_PQ + GB_HIST) {
        const int blk = b - GB_PQ;
        for (int i = threadIdx.x; i < NB; i += 256) sm.hloc[i] = 0;
        __syncthreads();
        const int base = blk * EPB;
        for (int j = 0; j < EPB; j += 256) {
            int e = base + j + threadIdx.x;
            if (e < NE) atomicAdd(&sm.hloc[ei[NE + e] >> 4], 1u);
        }
        __syncthreads();
        for (int i = threadIdx.x; i < NB; i += 256)
            H[(size_t)i * NBLK + blk] = sm.hloc[i];
    } else if (b < GB_PQ + GB_HIST + GB_G2) {
        if (flagw[0] == 1u) return;   // fallback only
        const int gb = b - GB_PQ - GB_HIST;
        for (int i = threadIdx.x; i < HIDN * 512; i += 256) sm.g.w2s[i] = w2[i];
        for (int i = threadIdx.x; i < 512; i += 256) sm.g.b2s[i] = b2[i];
        for (int i = threadIdx.x; i < QPB * HIDN; i += 256) {
            int qq = i / HIDN, k = i - qq * HIDN;
            float aq = (gb * QPB + qq + 0.5f) * (1.0f / (float)QG);
            sm.g.hs[qq][k] = fmaxf(fmaf(aq, w1[k], b1[k]), 0.f);
        }
        __syncthreads();
        for (int qq = 0; qq < QPB; ++qq) {
            const int q = gb * QPB + qq;
            int e = threadIdx.x;
            int ip = e >> 5, o = e & 31;
            float g0 = sm.g.b2s[(2 * ip) * OUTF + o];
            float g1 = sm.g.b2s[(2 * ip + 1) * OUTF + o];
#pragma unroll
            for (int k = 0; k < HIDN; ++k) {
                float h = sm.g.hs[qq][k];
                g0 = fmaf(h, sm.g.w2s[k * 512 + (2 * ip) * OUTF + o], g0);
                g1 = fmaf(h, sm.g.w2s[k * 512 + (2 * ip + 1) * OUTF + o], g1);
            }
            G2[(size_t)q * 256 + e] = packf16(g0, g1);
        }
    } else {
        if (flagw[0] == 1u) return;   // fallback only
        int t4 = ((b - GB_PQ - GB_HIST - GB_G2) * 256 + threadIdx.x) * 4;
        if (t4 < NN * INF_ / 2) {
            const float4* xp = reinterpret_cast<const float4*>(x) + (t4 >> 1);
            float4 va = xp[0];
            float4 vb = xp[1];
            xh[t4]     = packf16(va.x, va.y);
            xh[t4 + 1] = packf16(va.z, va.w);
            xh[t4 + 2] = packf16(vb.x, vb.y);
            xh[t4 + 3] = packf16(vb.z, vb.w);
        }
    }
}

// ---------- colsum: wave per bin, prefix over blocks ----------
__global__ __launch_bounds__(256) void colsum_k(const uint32_t* __restrict__ H,
                                                uint32_t* __restrict__ Bp,
                                                uint32_t* __restrict__ tot) {
    const int bin  = (blockIdx.x * 256 + threadIdx.x) >> 6;
    const int lane = threadIdx.x & 63;
    if (bin >= NB) return;
    const uint32_t* hr = H + (size_t)bin * NBLK;
    uint32_t* br = Bp + (size_t)bin * NBLK;
    uint32_t carry = 0;
    for (int b0 = 0; b0 < NBLK; b0 += 64) {
        int b = b0 + lane;
        uint32_t v = (b < NBLK) ? hr[b] : 0;
        uint32_t inc = v;
#pragma unroll
        for (int off = 1; off < 64; off <<= 1) {
            uint32_t t = __shfl_up(inc, off);
            if (lane >= off) inc += t;
        }
        if (b < NBLK) br[b] = carry + inc - v;
        carry += __shfl(inc, 63);
    }
    if (lane == 0) tot[bin] = carry;
}

// ---------- binscan ----------
__global__ __launch_bounds__(256) void binscan_k(const uint32_t* __restrict__ tot,
                                                 uint32_t* __restrict__ bstart) {
    __shared__ uint32_t part[256];
    const int t = threadIdx.x;
    uint32_t loc[SCH];
    uint32_t s = 0;
#pragma unroll
    for (int j = 0; j < SCH; ++j) {
        int idx = t * SCH + j;
        uint32_t v = (idx < NB) ? tot[idx] : 0;
        loc[j] = s;
        s += v;
    }
    part[t] = s;
    __syncthreads();
    for (int off = 1; off < 256; off <<= 1) {
        uint32_t add = (t >= off) ? part[t - off] : 0;
        __syncthreads();
        part[t] += add;
        __syncthreads();
    }
    uint32_t base = (t > 0) ? part[t - 1] : 0;
#pragma unroll
    for (int j = 0; j < SCH; ++j) {
        int idx = t * SCH + j;
        if (idx < NB) bstart[idx] = base + loc[j];
    }
    if (t == 255) bstart[NB] = part[255];
}

// ---------- scatter: 8B records (a_bits, src<<4|db) ----------
__global__ __launch_bounds__(256) void scatter_k(const int* __restrict__ ei,
                                                 const float* __restrict__ ea,
                                                 const uint32_t* __restrict__ Bp,
                                                 const uint32_t* __restrict__ bstart,
                                                 uint2* __restrict__ sorted) {
    __shared__ uint32_t cur[NB];                 // 12.5 KB
    for (int i = threadIdx.x; i < NB; i += 256) cur[i] = 0;
    __syncthreads();
    const int base = blockIdx.x * EPB;
    for (int j = 0; j < EPB; j += 256) {
        int e = base + j + threadIdx.x;
        if (e < NE) {
            int sn = ei[e];
            int d  = ei[NE + e];
            float a = ea[e];
            int bin = d >> 4;
            uint32_t r = atomicAdd(&cur[bin], 1u);
            uint32_t pos = bstart[bin] + Bp[(size_t)bin * NBLK + blockIdx.x] + r;
            sorted[pos] = make_uint2(__float_as_uint(a),
                                     ((uint32_t)sn << 4) | (uint32_t)(d & 15));
        }
    }
}

// ---------- fused: P+aQ fast path (flag) or G2 fallback; LDS max-agg; epilogue ----------
__global__ __launch_bounds__(256) void fused_k(const uint2* __restrict__ sorted,
                                               const uint32_t* __restrict__ bstart,
                                               const uint32_t* __restrict__ flagw,
                                               const float* __restrict__ x,
                                               const uint32_t* __restrict__ PQ,
                                               const uint32_t* __restrict__ xh,
                                               const uint32_t* __restrict__ G2,
                                               const float* __restrict__ root,
                                               const float* __restrict__ bias,
                                               const float* __restrict__ fcw,
                                               const float* __restrict__ fcb,
                                               float* __restrict__ out) {
    __shared__ uint2    ebuf[ECAP];              // 6 KB
    __shared__ uint32_t agg[DPB * ASTR];         // 2.1 KB
    __shared__ float rs[INF_ * OUTF];
    __shared__ float bs[OUTF];
    __shared__ float fws[OUTF * NC];
    __shared__ float fbs[NC];

    const int bin  = blockIdx.x;
    const int segs = (int)bstart[bin];
    const int cnt  = (int)bstart[bin + 1] - segs;
    const int scnt = cnt < ECAP ? cnt : ECAP;

    for (int i = threadIdx.x; i < scnt; i += 256) ebuf[i] = sorted[segs + i];
    for (int i = threadIdx.x; i < DPB * ASTR; i += 256) agg[i] = SENT;
    for (int i = threadIdx.x; i < INF_ * OUTF; i += 256) rs[i] = root[i];
    if (threadIdx.x < OUTF) bs[threadIdx.x] = bias[threadIdx.x];
    for (int i = threadIdx.x; i < OUTF * NC; i += 256) fws[i] = fcw[i];
    if (threadIdx.x < NC) fbs[threadIdx.x] = fcb[threadIdx.x];
    const uint32_t flag = flagw[0];
    __syncthreads();

    const int c   = threadIdx.x & 7;             // channels 4c..4c+3
    const int grp = threadIdx.x >> 3;            // 0..31 edge groups

    if (flag) {
        // ---- fast path: msg = P[src] + a*Q[src], 128 B/edge ----
        int it = grp;
        for (; it + 32 < cnt; it += 64) {
            uint2 rA = (it < ECAP) ? ebuf[it] : sorted[segs + it];
            int itB = it + 32;
            uint2 rB = (itB < ECAP) ? ebuf[itB] : sorted[segs + itB];
            float aA = __uint_as_float(rA.x), aB = __uint_as_float(rB.x);
            int sA = rA.y >> 4, sB = rB.y >> 4;
            int dA = rA.y & 15, dB = rB.y & 15;
            const uint2* pA = reinterpret_cast<const uint2*>(PQ + (size_t)sA * 32);
            const uint2* pB = reinterpret_cast<const uint2*>(PQ + (size_t)sB * 32);
            uint2 PuA = pA[c], QuA = pA[8 + c];
            uint2 PuB = pB[c], QuB = pB[8 + c];

            float a0 = fmaf(aA, f16lo(QuA.x), f16lo(PuA.x));
            float a1 = fmaf(aA, f16hi(QuA.x), f16hi(PuA.x));
            float a2 = fmaf(aA, f16lo(QuA.y), f16lo(PuA.y));
            float a3 = fmaf(aA, f16hi(QuA.y), f16hi(PuA.y));
            float b0 = fmaf(aB, f16lo(QuB.x), f16lo(PuB.x));
            float b1v = fmaf(aB, f16hi(QuB.x), f16hi(PuB.x));
            float b2v = fmaf(aB, f16lo(QuB.y), f16lo(PuB.y));
            float b3 = fmaf(aB, f16hi(QuB.y), f16hi(PuB.y));

            uint32_t* agA = &agg[dA * ASTR + c * 4];
            atomicMax(&agA[0], map_f(a0));
            atomicMax(&agA[1], map_f(a1));
            atomicMax(&agA[2], map_f(a2));
            atomicMax(&agA[3], map_f(a3));
            uint32_t* agB = &agg[dB * ASTR + c * 4];
            atomicMax(&agB[0], map_f(b0));
            atomicMax(&agB[1], map_f(b1v));
            atomicMax(&agB[2], map_f(b2v));
            atomicMax(&agB[3], map_f(b3));
        }
        if (it < cnt) {
            uint2 rA = (it < ECAP) ? ebuf[it] : sorted[segs + it];
            float aA = __uint_as_float(rA.x);
            int sA = rA.y >> 4;
            int dA = rA.y & 15;
            const uint2* pA = reinterpret_cast<const uint2*>(PQ + (size_t)sA * 32);
            uint2 PuA = pA[c], QuA = pA[8 + c];
            float a0 = fmaf(aA, f16lo(QuA.x), f16lo(PuA.x));
            float a1 = fmaf(aA, f16hi(QuA.x), f16hi(PuA.x));
            float a2 = fmaf(aA, f16lo(QuA.y), f16lo(PuA.y));
            float a3 = fmaf(aA, f16hi(QuA.y), f16hi(PuA.y));
            uint32_t* agA = &agg[dA * ASTR + c * 4];
            atomicMax(&agA[0], map_f(a0));
            atomicMax(&agA[1], map_f(a1));
            atomicMax(&agA[2], map_f(a2));
            atomicMax(&agA[3], map_f(a3));
        }
    } else {
        // ---- fallback: quantized G2 dot2 path (r15-proven) ----
        for (int it = grp; it < cnt; it += 32) {
            uint2 rec = (it < ECAP) ? ebuf[it] : sorted[segs + it];
            float a = __uint_as_float(rec.x);
            int src = rec.y >> 4;
            int db  = rec.y & 15;
            int q = (int)(a * (float)QG);
            q = q < 0 ? 0 : (q > QG - 1 ? QG - 1 : q);
            const uint4* xp = reinterpret_cast<const uint4*>(xh) + src * 2;
            uint4 hx0 = xp[0];
            uint4 hx1 = xp[1];
            const uint4* gq = reinterpret_cast<const uint4*>(G2) + (size_t)q * 64 + c;
            uint4 g0 = gq[0],  g1 = gq[8],  g2 = gq[16], g3 = gq[24];
            uint4 g4 = gq[32], g5 = gq[40], g6 = gq[48], g7 = gq[56];
            float p0 = 0.f, p1 = 0.f, p2 = 0.f, p3 = 0.f;
            p0 = dot2f(g0.x, hx0.x, p0); p1 = dot2f(g0.y, hx0.x, p1);
            p2 = dot2f(g0.z, hx0.x, p2); p3 = dot2f(g0.w, hx0.x, p3);
            p0 = dot2f(g1.x, hx0.y, p0); p1 = dot2f(g1.y, hx0.y, p1);
            p2 = dot2f(g1.z, hx0.y, p2); p3 = dot2f(g1.w, hx0.y, p3);
            p0 = dot2f(g2.x, hx0.z, p0); p1 = dot2f(g2.y, hx0.z, p1);
            p2 = dot2f(g2.z, hx0.z, p2); p3 = dot2f(g2.w, hx0.z, p3);
            p0 = dot2f(g3.x, hx0.w, p0); p1 = dot2f(g3.y, hx0.w, p1);
            p2 = dot2f(g3.z, hx0.w, p2); p3 = dot2f(g3.w, hx0.w, p3);
            p0 = dot2f(g4.x, hx1.x, p0); p1 = dot2f(g4.y, hx1.x, p1);
            p2 = dot2f(g4.z, hx1.x, p2); p3 = dot2f(g4.w, hx1.x, p3);
            p0 = dot2f(g5.x, hx1.y, p0); p1 = dot2f(g5.y, hx1.y, p1);
            p2 = dot2f(g5.z, hx1.y, p2); p3 = dot2f(g5.w, hx1.y, p3);
            p0 = dot2f(g6.x, hx1.z, p0); p1 = dot2f(g6.y, hx1.z, p1);
            p2 = dot2f(g6.z, hx1.z, p2); p3 = dot2f(g6.w, hx1.z, p3);
            p0 = dot2f(g7.x, hx1.w, p0); p1 = dot2f(g7.y, hx1.w, p1);
            p2 = dot2f(g7.z, hx1.w, p2); p3 = dot2f(g7.w, hx1.w, p3);
            uint32_t* ag = &agg[db * ASTR + c * 4];
            atomicMax(&ag[0], map_f(p0));
            atomicMax(&ag[1], map_f(p1));
            atomicMax(&ag[2], map_f(p2));
            atomicMax(&ag[3], map_f(p3));
        }
    }
    __syncthreads();

    // epilogue: 16 dsts x (8 lanes x 4 channels)
    {
        const int li8 = threadIdx.x & 7;
        const int dl  = threadIdx.x >> 3;
        const int n   = bin * DPB + dl;
        if (dl < DPB && n < NN) {
            const uint32_t* ar = &agg[dl * ASTR + li8 * 4];
            float av[4];
#pragma unroll
            for (int qq = 0; qq < 4; ++qq) {
                uint32_t u = ar[qq];
                av[qq] = (u == SENT) ? 0.f : unmap_f(u);
            }
            const float* xr = x + (size_t)n * INF_;
            float4 xa = *reinterpret_cast<const float4*>(xr);
            float4 xb = *reinterpret_cast<const float4*>(xr + 4);
            float4 xc = *reinterpret_cast<const float4*>(xr + 8);
            float4 xd = *reinterpret_cast<const float4*>(xr + 12);
            float xv[INF_] = {xa.x,xa.y,xa.z,xa.w, xb.x,xb.y,xb.z,xb.w,
                              xc.x,xc.y,xc.z,xc.w, xd.x,xd.y,xd.z,xd.w};
            float ov[4];
#pragma unroll
            for (int qq = 0; qq < 4; ++qq) {
                int oc = li8 * 4 + qq;
                float tv = av[qq] + bs[oc];
#pragma unroll
                for (int i = 0; i < INF_; ++i) tv = fmaf(xv[i], rs[i * OUTF + oc], tv);
                ov[qq] = (tv > 0.f) ? tv : expm1f(tv);   // ELU alpha=1
            }
            float lg[NC];
#pragma unroll
            for (int cc = 0; cc < NC; ++cc) {
                float tv = 0.f;
#pragma unroll
                for (int qq = 0; qq < 4; ++qq) tv = fmaf(ov[qq], fws[(li8 * 4 + qq) * NC + cc], tv);
                lg[cc] = tv;
            }
#pragma unroll
            for (int m = 1; m <= 4; m <<= 1) {
#pragma unroll
                for (int cc = 0; cc < NC; ++cc) lg[cc] += __shfl_xor(lg[cc], m);
            }
#pragma unroll
            for (int cc = 0; cc < NC; ++cc) lg[cc] += fbs[cc];

            float mx = lg[0];
#pragma unroll
            for (int cc = 1; cc < NC; ++cc) mx = fmaxf(mx, lg[cc]);
            float ssum = 0.f;
#pragma unroll
            for (int cc = 0; cc < NC; ++cc) ssum += expf(lg[cc] - mx);
            float lse = mx + logf(ssum);

            float* orow = out + (size_t)n * NC;
            orow[li8] = lg[li8] - lse;
            if (li8 < 2) orow[8 + li8] = lg[8 + li8] - lse;
        }
    }
}

extern "C" void kernel_launch(void* const* d_in, const int* in_sizes, int n_in,
                              void* d_out, int out_size, void* d_ws, size_t ws_size,
                              hipStream_t stream) {
    const float* x    = (const float*)d_in[0];
    const float* ea   = (const float*)d_in[1];
    const int*   ei   = (const int*)d_in[2];
    const float* w1   = (const float*)d_in[3];
    const float* b1   = (const float*)d_in[4];
    const float* w2   = (const float*)d_in[5];
    const float* b2   = (const float*)d_in[6];
    const float* root = (const float*)d_in[7];
    const float* bias = (const float*)d_in[8];
    const float* fcw  = (const float*)d_in[9];
    const float* fcb  = (const float*)d_in[10];
    float* out = (float*)d_out;

    size_t off = 0;
    auto alloc = [&](size_t bytes) {
        void* p = (char*)d_ws + off;
        off += (bytes + 255) & ~(size_t)255;
        return p;
    };
    uint32_t* flagw    = (uint32_t*)alloc(256);
    uint32_t* PQ       = (uint32_t*)alloc((size_t)NN * 32 * 4);                // 6.4 MB
    uint32_t* G2       = (uint32_t*)alloc((size_t)QG * 256 * 4);               // 2 MB (fallback)
    uint32_t* xh       = (uint32_t*)alloc((size_t)NN * INF_ * 2);              // 1.6 MB (fallback)
    uint32_t* H        = (uint32_t*)alloc((size_t)NB * NBLK * 4);              // 2.45 MB
    uint32_t* Bp       = (uint32_t*)alloc((size_t)NB * NBLK * 4);              // 2.45 MB
    uint32_t* tot      = (uint32_t*)alloc((size_t)NB * 4);
    uint32_t* bstart   = (uint32_t*)alloc((size_t)(NB + 1) * 4);
    uint2*    sorted   = (uint2*)alloc((size_t)NE * 8);                        // 6.4 MB

    flag_k<<<1, 64, 0, stream>>>(w1, b1, flagw);
    prep_k<<<GB_PQ + GB_HIST + GB_G2 + GB_XH, 256, 0, stream>>>(
        w1, b1, w2, b2, x, ei, flagw, PQ, G2, xh, H);
    colsum_k<<<(NB * 64 + 255) / 256, 256, 0, stream>>>(H, Bp, tot);
    binscan_k<<<1, 256, 0, stream>>>(tot, bstart);
    scatter_k<<<NBLK, 256, 0, stream>>>(ei, ea, Bp, bstart, sorted);
    fused_k<<<NB, 256, 0, stream>>>(sorted, bstart, flagw, x, PQ, xh, G2,
                                    root, bias, fcw, fcb, out);
}

// Round 18
// 81.688 us; speedup vs baseline: 1.1914x; 1.0623x over previous
//
#include <hip/hip_runtime.h>
#include <hip/hip_bf16.h>
#include <stdint.h>

#define NN   50000
#define NE   800000
#define INF_ 16
#define OUTF 32
#define HIDN 25
#define NC   10
#define QG   2048                 // fallback-path quantization levels
#define QPB  16
#define DPB  16                   // dsts per bucket
#define NB   3125                 // 50000/16
#define EPB  4096
#define NBLK 196                  // ceil(NE/EPB)
#define ASTR 33
#define ECAP 768
#define SCH  13                   // ceil(NB/256)

#define SENT 0x007FFFFFu          // map_f(-inf)

#define GB_PQ   1563              // PQ-prep blocks (32 nodes each)
#define GB_HIST NBLK
#define GB_G2   128               // fallback G2 prep (flag-gated)
#define GB_XH   391               // fallback xh prep (flag-gated)

typedef _Float16 f16x2 __attribute__((ext_vector_type(2)));

__device__ __forceinline__ uint32_t map_f(float f) {
    uint32_t b = __float_as_uint(f);
    return (b & 0x80000000u) ? ~b : (b | 0x80000000u);
}
__device__ __forceinline__ float unmap_f(uint32_t u) {
    return (u & 0x80000000u) ? __uint_as_float(u ^ 0x80000000u)
                             : __uint_as_float(~u);
}
__device__ __forceinline__ float f16lo(uint32_t u) {
    union { uint16_t s; _Float16 h; } v; v.s = (uint16_t)(u & 0xFFFF);
    return (float)v.h;
}
__device__ __forceinline__ float f16hi(uint32_t u) {
    union { uint16_t s; _Float16 h; } v; v.s = (uint16_t)(u >> 16);
    return (float)v.h;
}
__device__ __forceinline__ uint32_t packf16(float a, float b) {
    union { uint32_t u; f16x2 h; } p;
    p.h[0] = (_Float16)a; p.h[1] = (_Float16)b;
    return p.u;
}
__device__ __forceinline__ float dot2f(uint32_t g, uint32_t xb, float acc) {
#if __has_builtin(__builtin_amdgcn_fdot2)
    union { uint32_t u; f16x2 h; } ug, ux;
    ug.u = g; ux.u = xb;
    return __builtin_amdgcn_fdot2(ug.h, ux.h, acc, false);
#else
    return fmaf(f16lo(g), f16lo(xb), fmaf(f16hi(g), f16hi(xb), acc));
#endif
}

// single-segment flag: no ReLU breakpoint strictly inside (0,1). Uniform across threads.
__device__ __forceinline__ uint32_t calc_flag(const float* w1, const float* b1) {
    uint32_t flag = 1;
    for (int k = 0; k < HIDN; ++k) {
        float w = w1[k], b = b1[k];
        if (w != 0.f) {
            float t = -b / w;
            if (t > 0.f && t < 1.f) flag = 0;
        }
    }
    return flag;
}

// ---------- prep: [0,1563) PQ; then hist; then gated G2; then gated xh ----------
__global__ __launch_bounds__(256) void prep_k(const float* __restrict__ w1,
                                              const float* __restrict__ b1,
                                              const float* __restrict__ w2,
                                              const float* __restrict__ b2,
                                              const float* __restrict__ x,
                                              const int* __restrict__ ei,
                                              uint32_t* __restrict__ PQ,
                                              uint32_t* __restrict__ G2,
                                              uint32_t* __restrict__ xh,
                                              uint32_t* __restrict__ H) {
    __shared__ union {
        struct { float ca[512]; float cb[512]; } pq;    // 4 KB
        uint32_t hloc[NB];                              // 12.5 KB
        float hs[QPB][HIDN];                            // 1.6 KB
    } sm;

    const int b = blockIdx.x;
    if (b < GB_PQ) {
        // ---- P/Q tables, 32 nodes/block, 8 lanes/node ----
        uint32_t mask = 0;
        for (int k = 0; k < HIDN; ++k)
            if (fmaf(0.5f, w1[k], b1[k]) > 0.f) mask |= (1u << k);
        for (int e = threadIdx.x; e < 512; e += 256) {
            float ca = b2[e], cb = 0.f;
            for (int k = 0; k < HIDN; ++k) {
                if ((mask >> k) & 1u) {
                    float wv = w2[k * 512 + e];
                    ca = fmaf(b1[k], wv, ca);
                    cb = fmaf(w1[k], wv, cb);
                }
            }
            sm.pq.ca[e] = ca;
            sm.pq.cb[e] = cb;
        }
        __syncthreads();
        const int c = threadIdx.x & 7;               // channels 4c..4c+3
        const int n = b * 32 + (threadIdx.x >> 3);
        if (n < NN) {
            float xv[INF_];
            const float* xr = x + (size_t)n * INF_;
#pragma unroll
            for (int i = 0; i < INF_; i += 4) {
                float4 v = *reinterpret_cast<const float4*>(xr + i);
                xv[i] = v.x; xv[i+1] = v.y; xv[i+2] = v.z; xv[i+3] = v.w;
            }
            float P[4], Q[4];
#pragma unroll
            for (int j = 0; j < 4; ++j) {
                int o = c * 4 + j;
                float p = 0.f, q = 0.f;
#pragma unroll
                for (int i = 0; i < INF_; ++i) {
                    p = fmaf(xv[i], sm.pq.ca[i * 32 + o], p);
                    q = fmaf(xv[i], sm.pq.cb[i * 32 + o], q);
                }
                P[j] = p; Q[j] = q;
            }
            uint32_t* row = PQ + (size_t)n * 32;
            row[2*c]      = packf16(P[0], P[1]);
            row[2*c + 1]  = packf16(P[2], P[3]);
            row[16 + 2*c]     = packf16(Q[0], Q[1]);
            row[16 + 2*c + 1] = packf16(Q[2], Q[3]);
        }
    } else if (b < GB_PQ + GB_HIST) {
        const int blk = b - GB_PQ;
        for (int i = threadIdx.x; i < NB; i += 256) sm.hloc[i] = 0;
        __syncthreads();
        const int base = blk * EPB;
        for (int j = 0; j < EPB; j += 256) {
            int e = base + j + threadIdx.x;
            if (e < NE) atomicAdd(&sm.hloc[ei[NE + e] >> 4], 1u);
        }
        __syncthreads();
        for (int i = threadIdx.x; i < NB; i += 256)
            H[(size_t)i * NBLK + blk] = sm.hloc[i];
    } else if (b < GB_PQ + GB_HIST + GB_G2) {
        if (calc_flag(w1, b1)) return;               // fallback only
        const int gb = b - GB_PQ - GB_HIST;
        for (int i = threadIdx.x; i < QPB * HIDN; i += 256) {
            int qq = i / HIDN, k = i - qq * HIDN;
            float aq = (gb * QPB + qq + 0.5f) * (1.0f / (float)QG);
            sm.hs[qq][k] = fmaxf(fmaf(aq, w1[k], b1[k]), 0.f);
        }
        __syncthreads();
        for (int qq = 0; qq < QPB; ++qq) {
            const int q = gb * QPB + qq;
            int e = threadIdx.x;
            int ip = e >> 5, o = e & 31;
            float g0 = b2[(2 * ip) * OUTF + o];
            float g1 = b2[(2 * ip + 1) * OUTF + o];
#pragma unroll
            for (int k = 0; k < HIDN; ++k) {
                float h = sm.hs[qq][k];
                g0 = fmaf(h, w2[k * 512 + (2 * ip) * OUTF + o], g0);
                g1 = fmaf(h, w2[k * 512 + (2 * ip + 1) * OUTF + o], g1);
            }
            G2[(size_t)q * 256 + e] = packf16(g0, g1);
        }
    } else {
        if (calc_flag(w1, b1)) return;               // fallback only
        int t4 = ((b - GB_PQ - GB_HIST - GB_G2) * 256 + threadIdx.x) * 4;
        if (t4 < NN * INF_ / 2) {
            const float4* xp = reinterpret_cast<const float4*>(x) + (t4 >> 1);
            float4 va = xp[0];
            float4 vb = xp[1];
            xh[t4]     = packf16(va.x, va.y);
            xh[t4 + 1] = packf16(va.z, va.w);
            xh[t4 + 2] = packf16(vb.x, vb.y);
            xh[t4 + 3] = packf16(vb.z, vb.w);
        }
    }
}

// ---------- colsum: wave per bin, prefix over blocks ----------
__global__ __launch_bounds__(256) void colsum_k(const uint32_t* __restrict__ H,
                                                uint32_t* __restrict__ Bp,
                                                uint32_t* __restrict__ tot) {
    const int bin  = (blockIdx.x * 256 + threadIdx.x) >> 6;
    const int lane = threadIdx.x & 63;
    if (bin >= NB) return;
    const uint32_t* hr = H + (size_t)bin * NBLK;
    uint32_t* br = Bp + (size_t)bin * NBLK;
    uint32_t carry = 0;
    for (int b0 = 0; b0 < NBLK; b0 += 64) {
        int b = b0 + lane;
        uint32_t v = (b < NBLK) ? hr[b] : 0;
        uint32_t inc = v;
#pragma unroll
        for (int off = 1; off < 64; off <<= 1) {
            uint32_t t = __shfl_up(inc, off);
            if (lane >= off) inc += t;
        }
        if (b < NBLK) br[b] = carry + inc - v;
        carry += __shfl(inc, 63);
    }
    if (lane == 0) tot[bin] = carry;
}

// ---------- binscan ----------
__global__ __launch_bounds__(256) void binscan_k(const uint32_t* __restrict__ tot,
                                                 uint32_t* __restrict__ bstart) {
    __shared__ uint32_t part[256];
    const int t = threadIdx.x;
    uint32_t loc[SCH];
    uint32_t s = 0;
#pragma unroll
    for (int j = 0; j < SCH; ++j) {
        int idx = t * SCH + j;
        uint32_t v = (idx < NB) ? tot[idx] : 0;
        loc[j] = s;
        s += v;
    }
    part[t] = s;
    __syncthreads();
    for (int off = 1; off < 256; off <<= 1) {
        uint32_t add = (t >= off) ? part[t - off] : 0;
        __syncthreads();
        part[t] += add;
        __syncthreads();
    }
    uint32_t base = (t > 0) ? part[t - 1] : 0;
#pragma unroll
    for (int j = 0; j < SCH; ++j) {
        int idx = t * SCH + j;
        if (idx < NB) bstart[idx] = base + loc[j];
    }
    if (t == 255) bstart[NB] = part[255];
}

// ---------- scatter: 8B records (a_bits, src<<4|db) ----------
__global__ __launch_bounds__(256) void scatter_k(const int* __restrict__ ei,
                                                 const float* __restrict__ ea,
                                                 const uint32_t* __restrict__ Bp,
                                                 const uint32_t* __restrict__ bstart,
                                                 uint2* __restrict__ sorted) {
    __shared__ uint32_t cur[NB];                 // 12.5 KB
    for (int i = threadIdx.x; i < NB; i += 256) cur[i] = 0;
    __syncthreads();
    const int base = blockIdx.x * EPB;
    for (int j = 0; j < EPB; j += 256) {
        int e = base + j + threadIdx.x;
        if (e < NE) {
            int sn = ei[e];
            int d  = ei[NE + e];
            float a = ea[e];
            int bin = d >> 4;
            uint32_t r = atomicAdd(&cur[bin], 1u);
            uint32_t pos = bstart[bin] + Bp[(size_t)bin * NBLK + blockIdx.x] + r;
            sorted[pos] = make_uint2(__float_as_uint(a),
                                     ((uint32_t)sn << 4) | (uint32_t)(d & 15));
        }
    }
}

// ---------- fused: P+aQ fast path (flag) or G2 fallback; LDS max-agg; epilogue ----------
__global__ __launch_bounds__(256) void fused_k(const uint2* __restrict__ sorted,
                                               const uint32_t* __restrict__ bstart,
                                               const float* __restrict__ w1,
                                               const float* __restrict__ b1,
                                               const float* __restrict__ x,
                                               const uint32_t* __restrict__ PQ,
                                               const uint32_t* __restrict__ xh,
                                               const uint32_t* __restrict__ G2,
                                               const float* __restrict__ root,
                                               const float* __restrict__ bias,
                                               const float* __restrict__ fcw,
                                               const float* __restrict__ fcb,
                                               float* __restrict__ out) {
    __shared__ uint2    ebuf[ECAP];              // 6 KB
    __shared__ uint32_t agg[DPB * ASTR];         // 2.1 KB
    __shared__ float rs[INF_ * OUTF];
    __shared__ float bs[OUTF];
    __shared__ float fws[OUTF * NC];
    __shared__ float fbs[NC];

    const int bin  = blockIdx.x;
    const int segs = (int)bstart[bin];
    const int cnt  = (int)bstart[bin + 1] - segs;
    const int scnt = cnt < ECAP ? cnt : ECAP;

    for (int i = threadIdx.x; i < scnt; i += 256) ebuf[i] = sorted[segs + i];
    for (int i = threadIdx.x; i < DPB * ASTR; i += 256) agg[i] = SENT;
    for (int i = threadIdx.x; i < INF_ * OUTF; i += 256) rs[i] = root[i];
    if (threadIdx.x < OUTF) bs[threadIdx.x] = bias[threadIdx.x];
    for (int i = threadIdx.x; i < OUTF * NC; i += 256) fws[i] = fcw[i];
    if (threadIdx.x < NC) fbs[threadIdx.x] = fcb[threadIdx.x];
    const uint32_t flag = calc_flag(w1, b1);
    __syncthreads();

    const int c   = threadIdx.x & 7;             // channels 4c..4c+3
    const int grp = threadIdx.x >> 3;            // 0..31 edge groups

    if (flag) {
        // ---- fast path: msg = P[src] + a*Q[src], 128 B/edge ----
        int it = grp;
        for (; it + 32 < cnt; it += 64) {
            uint2 rA = (it < ECAP) ? ebuf[it] : sorted[segs + it];
            int itB = it + 32;
            uint2 rB = (itB < ECAP) ? ebuf[itB] : sorted[segs + itB];
            float aA = __uint_as_float(rA.x), aB = __uint_as_float(rB.x);
            int sA = rA.y >> 4, sB = rB.y >> 4;
            int dA = rA.y & 15, dB = rB.y & 15;
            const uint2* pA = reinterpret_cast<const uint2*>(PQ + (size_t)sA * 32);
            const uint2* pB = reinterpret_cast<const uint2*>(PQ + (size_t)sB * 32);
            uint2 PuA = pA[c], QuA = pA[8 + c];
            uint2 PuB = pB[c], QuB = pB[8 + c];

            float a0 = fmaf(aA, f16lo(QuA.x), f16lo(PuA.x));
            float a1 = fmaf(aA, f16hi(QuA.x), f16hi(PuA.x));
            float a2 = fmaf(aA, f16lo(QuA.y), f16lo(PuA.y));
            float a3 = fmaf(aA, f16hi(QuA.y), f16hi(PuA.y));
            float b0 = fmaf(aB, f16lo(QuB.x), f16lo(PuB.x));
            float b1v = fmaf(aB, f16hi(QuB.x), f16hi(PuB.x));
            float b2v = fmaf(aB, f16lo(QuB.y), f16lo(PuB.y));
            float b3 = fmaf(aB, f16hi(QuB.y), f16hi(PuB.y));

            uint32_t* agA = &agg[dA * ASTR + c * 4];
            atomicMax(&agA[0], map_f(a0));
            atomicMax(&agA[1], map_f(a1));
            atomicMax(&agA[2], map_f(a2));
            atomicMax(&agA[3], map_f(a3));
            uint32_t* agB = &agg[dB * ASTR + c * 4];
            atomicMax(&agB[0], map_f(b0));
            atomicMax(&agB[1], map_f(b1v));
            atomicMax(&agB[2], map_f(b2v));
            atomicMax(&agB[3], map_f(b3));
        }
        if (it < cnt) {
            uint2 rA = (it < ECAP) ? ebuf[it] : sorted[segs + it];
            float aA = __uint_as_float(rA.x);
            int sA = rA.y >> 4;
            int dA = rA.y & 15;
            const uint2* pA = reinterpret_cast<const uint2*>(PQ + (size_t)sA * 32);
            uint2 PuA = pA[c], QuA = pA[8 + c];
            float a0 = fmaf(aA, f16lo(QuA.x), f16lo(PuA.x));
            float a1 = fmaf(aA, f16hi(QuA.x), f16hi(PuA.x));
            float a2 = fmaf(aA, f16lo(QuA.y), f16lo(PuA.y));
            float a3 = fmaf(aA, f16hi(QuA.y), f16hi(PuA.y));
            uint32_t* agA = &agg[dA * ASTR + c * 4];
            atomicMax(&agA[0], map_f(a0));
            atomicMax(&agA[1], map_f(a1));
            atomicMax(&agA[2], map_f(a2));
            atomicMax(&agA[3], map_f(a3));
        }
    } else {
        // ---- fallback: quantized G2 dot2 path ----
        for (int it = grp; it < cnt; it += 32) {
            uint2 rec = (it < ECAP) ? ebuf[it] : sorted[segs + it];
            float a = __uint_as_float(rec.x);
            int src = rec.y >> 4;
            int db  = rec.y & 15;
            int q = (int)(a * (float)QG);
            q = q < 0 ? 0 : (q > QG - 1 ? QG - 1 : q);
            const uint4* xp = reinterpret_cast<const uint4*>(xh) + src * 2;
            uint4 hx0 = xp[0];
            uint4 hx1 = xp[1];
            const uint4* gq = reinterpret_cast<const uint4*>(G2) + (size_t)q * 64 + c;
            uint4 g0 = gq[0],  g1 = gq[8],  g2 = gq[16], g3 = gq[24];
            uint4 g4 = gq[32], g5 = gq[40], g6 = gq[48], g7 = gq[56];
            float p0 = 0.f, p1 = 0.f, p2 = 0.f, p3 = 0.f;
            p0 = dot2f(g0.x, hx0.x, p0); p1 = dot2f(g0.y, hx0.x, p1);
            p2 = dot2f(g0.z, hx0.x, p2); p3 = dot2f(g0.w, hx0.x, p3);
            p0 = dot2f(g1.x, hx0.y, p0); p1 = dot2f(g1.y, hx0.y, p1);
            p2 = dot2f(g1.z, hx0.y, p2); p3 = dot2f(g1.w, hx0.y, p3);
            p0 = dot2f(g2.x, hx0.z, p0); p1 = dot2f(g2.y, hx0.z, p1);
            p2 = dot2f(g2.z, hx0.z, p2); p3 = dot2f(g2.w, hx0.z, p3);
            p0 = dot2f(g3.x, hx0.w, p0); p1 = dot2f(g3.y, hx0.w, p1);
            p2 = dot2f(g3.z, hx0.w, p2); p3 = dot2f(g3.w, hx0.w, p3);
            p0 = dot2f(g4.x, hx1.x, p0); p1 = dot2f(g4.y, hx1.x, p1);
            p2 = dot2f(g4.z, hx1.x, p2); p3 = dot2f(g4.w, hx1.x, p3);
            p0 = dot2f(g5.x, hx1.y, p0); p1 = dot2f(g5.y, hx1.y, p1);
            p2 = dot2f(g5.z, hx1.y, p2); p3 = dot2f(g5.w, hx1.y, p3);
            p0 = dot2f(g6.x, hx1.z, p0); p1 = dot2f(g6.y, hx1.z, p1);
            p2 = dot2f(g6.z, hx1.z, p2); p3 = dot2f(g6.w, hx1.z, p3);
            p0 = dot2f(g7.x, hx1.w, p0); p1 = dot2f(g7.y, hx1.w, p1);
            p2 = dot2f(g7.z, hx1.w, p2); p3 = dot2f(g7.w, hx1.w, p3);
            uint32_t* ag = &agg[db * ASTR + c * 4];
            atomicMax(&ag[0], map_f(p0));
            atomicMax(&ag[1], map_f(p1));
            atomicMax(&ag[2], map_f(p2));
            atomicMax(&ag[3], map_f(p3));
        }
    }
    __syncthreads();

    // epilogue: 16 dsts x (8 lanes x 4 channels)
    {
        const int li8 = threadIdx.x & 7;
        const int dl  = threadIdx.x >> 3;
        const int n   = bin * DPB + dl;
        if (dl < DPB && n < NN) {
            const uint32_t* ar = &agg[dl * ASTR + li8 * 4];
            float av[4];
#pragma unroll
            for (int qq = 0; qq < 4; ++qq) {
                uint32_t u = ar[qq];
                av[qq] = (u == SENT) ? 0.f : unmap_f(u);
            }
            const float* xr = x + (size_t)n * INF_;
            float4 xa = *reinterpret_cast<const float4*>(xr);
            float4 xb = *reinterpret_cast<const float4*>(xr + 4);
            float4 xc = *reinterpret_cast<const float4*>(xr + 8);
            float4 xd = *reinterpret_cast<const float4*>(xr + 12);
            float xv[INF_] = {xa.x,xa.y,xa.z,xa.w, xb.x,xb.y,xb.z,xb.w,
                              xc.x,xc.y,xc.z,xc.w, xd.x,xd.y,xd.z,xd.w};
            float ov[4];
#pragma unroll
            for (int qq = 0; qq < 4; ++qq) {
                int oc = li8 * 4 + qq;
                float tv = av[qq] + bs[oc];
#pragma unroll
                for (int i = 0; i < INF_; ++i) tv = fmaf(xv[i], rs[i * OUTF + oc], tv);
                ov[qq] = (tv > 0.f) ? tv : expm1f(tv);   // ELU alpha=1
            }
            float lg[NC];
#pragma unroll
            for (int cc = 0; cc < NC; ++cc) {
                float tv = 0.f;
#pragma unroll
                for (int qq = 0; qq < 4; ++qq) tv = fmaf(ov[qq], fws[(li8 * 4 + qq) * NC + cc], tv);
                lg[cc] = tv;
            }
#pragma unroll
            for (int m = 1; m <= 4; m <<= 1) {
#pragma unroll
                for (int cc = 0; cc < NC; ++cc) lg[cc] += __shfl_xor(lg[cc], m);
            }
#pragma unroll
            for (int cc = 0; cc < NC; ++cc) lg[cc] += fbs[cc];

            float mx = lg[0];
#pragma unroll
            for (int cc = 1; cc < NC; ++cc) mx = fmaxf(mx, lg[cc]);
            float ssum = 0.f;
#pragma unroll
            for (int cc = 0; cc < NC; ++cc) ssum += expf(lg[cc] - mx);
            float lse = mx + logf(ssum);

            float* orow = out + (size_t)n * NC;
            orow[li8] = lg[li8] - lse;
            if (li8 < 2) orow[8 + li8] = lg[8 + li8] - lse;
        }
    }
}

extern "C" void kernel_launch(void* const* d_in, const int* in_sizes, int n_in,
                              void* d_out, int out_size, void* d_ws, size_t ws_size,
                              hipStream_t stream) {
    const float* x    = (const float*)d_in[0];
    const float* ea   = (const float*)d_in[1];
    const int*   ei   = (const int*)d_in[2];
    const float* w1   = (const float*)d_in[3];
    const float* b1   = (const float*)d_in[4];
    const float* w2   = (const float*)d_in[5];
    const float* b2   = (const float*)d_in[6];
    const float* root = (const float*)d_in[7];
    const float* bias = (const float*)d_in[8];
    const float* fcw  = (const float*)d_in[9];
    const float* fcb  = (const float*)d_in[10];
    float* out = (float*)d_out;

    size_t off = 0;
    auto alloc = [&](size_t bytes) {
        void* p = (char*)d_ws + off;
        off += (bytes + 255) & ~(size_t)255;
        return p;
    };
    uint32_t* PQ       = (uint32_t*)alloc((size_t)NN * 32 * 4);                // 6.4 MB
    uint32_t* G2       = (uint32_t*)alloc((size_t)QG * 256 * 4);               // 2 MB (fallback)
    uint32_t* xh       = (uint32_t*)alloc((size_t)NN * INF_ * 2);              // 1.6 MB (fallback)
    uint32_t* H        = (uint32_t*)alloc((size_t)NB * NBLK * 4);              // 2.45 MB
    uint32_t* Bp       = (uint32_t*)alloc((size_t)NB * NBLK * 4);              // 2.45 MB
    uint32_t* tot      = (uint32_t*)alloc((size_t)NB * 4);
    uint32_t* bstart   = (uint32_t*)alloc((size_t)(NB + 1) * 4);
    uint2*    sorted   = (uint2*)alloc((size_t)NE * 8);                        // 6.4 MB

    prep_k<<<GB_PQ + GB_HIST + GB_G2 + GB_XH, 256, 0, stream>>>(
        w1, b1, w2, b2, x, ei, PQ, G2, xh, H);
    colsum_k<<<(NB * 64 + 255) / 256, 256, 0, stream>>>(H, Bp, tot);
    binscan_k<<<1, 256, 0, stream>>>(tot, bstart);
    scatter_k<<<NBLK, 256, 0, stream>>>(ei, ea, Bp, bstart, sorted);
    fused_k<<<NB, 256, 0, stream>>>(sorted, bstart, w1, b1, x, PQ, xh, G2,
                                    root, bias, fcw, fcb, out);
}

// Round 19
// 78.722 us; speedup vs baseline: 1.2362x; 1.0377x over previous
//
#include <hip/hip_runtime.h>
#include <hip/hip_bf16.h>
#include <stdint.h>

#define NN   50000
#define NE   800000
#define INF_ 16
#define OUTF 32
#define HIDN 25
#define NC   10
#define QG   2048                 // fallback-path quantization levels
#define QPB  16
#define DPB  16                   // dsts per bucket
#define NB   3125                 // 50000/16
#define EPB  4096
#define NBLK 196                  // ceil(NE/EPB)
#define ASTR 33
#define ECAP 768
#define SCH  13                   // ceil(NB/256)

#define SENT 0x007FFFFFu          // map_f(-inf)

#define GB_PQ   1563              // PQ-prep blocks (32 nodes each)
#define GB_HIST NBLK
#define GB_G2   128               // fallback G2 prep (flag-gated)
#define GB_XH   391               // fallback xh prep (flag-gated)

typedef _Float16 f16x2 __attribute__((ext_vector_type(2)));

__device__ __forceinline__ uint32_t map_f(float f) {
    uint32_t b = __float_as_uint(f);
    return (b & 0x80000000u) ? ~b : (b | 0x80000000u);
}
__device__ __forceinline__ float unmap_f(uint32_t u) {
    return (u & 0x80000000u) ? __uint_as_float(u ^ 0x80000000u)
                             : __uint_as_float(~u);
}
__device__ __forceinline__ float f16lo(uint32_t u) {
    union { uint16_t s; _Float16 h; } v; v.s = (uint16_t)(u & 0xFFFF);
    return (float)v.h;
}
__device__ __forceinline__ float f16hi(uint32_t u) {
    union { uint16_t s; _Float16 h; } v; v.s = (uint16_t)(u >> 16);
    return (float)v.h;
}
__device__ __forceinline__ uint32_t packf16(float a, float b) {
    union { uint32_t u; f16x2 h; } p;
    p.h[0] = (_Float16)a; p.h[1] = (_Float16)b;
    return p.u;
}
__device__ __forceinline__ float dot2f(uint32_t g, uint32_t xb, float acc) {
#if __has_builtin(__builtin_amdgcn_fdot2)
    union { uint32_t u; f16x2 h; } ug, ux;
    ug.u = g; ux.u = xb;
    return __builtin_amdgcn_fdot2(ug.h, ux.h, acc, false);
#else
    return fmaf(f16lo(g), f16lo(xb), fmaf(f16hi(g), f16hi(xb), acc));
#endif
}

// single-segment flag: no ReLU breakpoint strictly inside (0,1). Uniform across threads.
__device__ __forceinline__ uint32_t calc_flag(const float* w1, const float* b1) {
    uint32_t flag = 1;
    for (int k = 0; k < HIDN; ++k) {
        float w = w1[k], b = b1[k];
        if (w != 0.f) {
            float t = -b / w;
            if (t > 0.f && t < 1.f) flag = 0;
        }
    }
    return flag;
}

// ---------- prep: [0,1563) PQ; then hist; then gated G2; then gated xh ----------
__global__ __launch_bounds__(256) void prep_k(const float* __restrict__ w1,
                                              const float* __restrict__ b1,
                                              const float* __restrict__ w2,
                                              const float* __restrict__ b2,
                                              const float* __restrict__ x,
                                              const int* __restrict__ ei,
                                              uint32_t* __restrict__ PQ,
                                              uint32_t* __restrict__ G2,
                                              uint32_t* __restrict__ xh,
                                              uint32_t* __restrict__ H) {
    __shared__ union {
        struct { float ca[512]; float cb[512]; } pq;    // 4 KB
        uint32_t hloc[NB];                              // 12.5 KB
        float hs[QPB][HIDN];                            // 1.6 KB
    } sm;

    const int b = blockIdx.x;
    if (b < GB_PQ) {
        uint32_t mask = 0;
        for (int k = 0; k < HIDN; ++k)
            if (fmaf(0.5f, w1[k], b1[k]) > 0.f) mask |= (1u << k);
        for (int e = threadIdx.x; e < 512; e += 256) {
            float ca = b2[e], cb = 0.f;
            for (int k = 0; k < HIDN; ++k) {
                if ((mask >> k) & 1u) {
                    float wv = w2[k * 512 + e];
                    ca = fmaf(b1[k], wv, ca);
                    cb = fmaf(w1[k], wv, cb);
                }
            }
            sm.pq.ca[e] = ca;
            sm.pq.cb[e] = cb;
        }
        __syncthreads();
        const int c = threadIdx.x & 7;               // channels 4c..4c+3
        const int n = b * 32 + (threadIdx.x >> 3);
        if (n < NN) {
            float xv[INF_];
            const float* xr = x + (size_t)n * INF_;
#pragma unroll
            for (int i = 0; i < INF_; i += 4) {
                float4 v = *reinterpret_cast<const float4*>(xr + i);
                xv[i] = v.x; xv[i+1] = v.y; xv[i+2] = v.z; xv[i+3] = v.w;
            }
            float P[4], Q[4];
#pragma unroll
            for (int j = 0; j < 4; ++j) {
                int o = c * 4 + j;
                float p = 0.f, q = 0.f;
#pragma unroll
                for (int i = 0; i < INF_; ++i) {
                    p = fmaf(xv[i], sm.pq.ca[i * 32 + o], p);
                    q = fmaf(xv[i], sm.pq.cb[i * 32 + o], q);
                }
                P[j] = p; Q[j] = q;
            }
            uint2* row = reinterpret_cast<uint2*>(PQ + (size_t)n * 32);
            row[c]     = make_uint2(packf16(P[0], P[1]), packf16(P[2], P[3]));
            row[8 + c] = make_uint2(packf16(Q[0], Q[1]), packf16(Q[2], Q[3]));
        }
    } else if (b < GB_PQ + GB_HIST) {
        const int blk = b - GB_PQ;
        for (int i = threadIdx.x; i < NB; i += 256) sm.hloc[i] = 0;
        __syncthreads();
        const int base = blk * EPB;
        for (int j = 0; j < EPB; j += 256) {
            int e = base + j + threadIdx.x;
            if (e < NE) atomicAdd(&sm.hloc[ei[NE + e] >> 4], 1u);
        }
        __syncthreads();
        for (int i = threadIdx.x; i < NB; i += 256)
            H[(size_t)i * NBLK + blk] = sm.hloc[i];
    } else if (b < GB_PQ + GB_HIST + GB_G2) {
        if (calc_flag(w1, b1)) return;               // fallback only
        const int gb = b - GB_PQ - GB_HIST;
        for (int i = threadIdx.x; i < QPB * HIDN; i += 256) {
            int qq = i / HIDN, k = i - qq * HIDN;
            float aq = (gb * QPB + qq + 0.5f) * (1.0f / (float)QG);
            sm.hs[qq][k] = fmaxf(fmaf(aq, w1[k], b1[k]), 0.f);
        }
        __syncthreads();
        for (int qq = 0; qq < QPB; ++qq) {
            const int q = gb * QPB + qq;
            int e = threadIdx.x;
            int ip = e >> 5, o = e & 31;
            float g0 = b2[(2 * ip) * OUTF + o];
            float g1 = b2[(2 * ip + 1) * OUTF + o];
#pragma unroll
            for (int k = 0; k < HIDN; ++k) {
                float h = sm.hs[qq][k];
                g0 = fmaf(h, w2[k * 512 + (2 * ip) * OUTF + o], g0);
                g1 = fmaf(h, w2[k * 512 + (2 * ip + 1) * OUTF + o], g1);
            }
            G2[(size_t)q * 256 + e] = packf16(g0, g1);
        }
    } else {
        if (calc_flag(w1, b1)) return;               // fallback only
        int t4 = ((b - GB_PQ - GB_HIST - GB_G2) * 256 + threadIdx.x) * 4;
        if (t4 < NN * INF_ / 2) {
            const float4* xp = reinterpret_cast<const float4*>(x) + (t4 >> 1);
            float4 va = xp[0];
            float4 vb = xp[1];
            xh[t4]     = packf16(va.x, va.y);
            xh[t4 + 1] = packf16(va.z, va.w);
            xh[t4 + 2] = packf16(vb.x, vb.y);
            xh[t4 + 3] = packf16(vb.z, vb.w);
        }
    }
}

// ---------- colsum: wave per bin, prefix over blocks ----------
__global__ __launch_bounds__(256) void colsum_k(const uint32_t* __restrict__ H,
                                                uint32_t* __restrict__ Bp,
                                                uint32_t* __restrict__ tot) {
    const int bin  = (blockIdx.x * 256 + threadIdx.x) >> 6;
    const int lane = threadIdx.x & 63;
    if (bin >= NB) return;
    const uint32_t* hr = H + (size_t)bin * NBLK;
    uint32_t* br = Bp + (size_t)bin * NBLK;
    uint32_t carry = 0;
    for (int b0 = 0; b0 < NBLK; b0 += 64) {
        int b = b0 + lane;
        uint32_t v = (b < NBLK) ? hr[b] : 0;
        uint32_t inc = v;
#pragma unroll
        for (int off = 1; off < 64; off <<= 1) {
            uint32_t t = __shfl_up(inc, off);
            if (lane >= off) inc += t;
        }
        if (b < NBLK) br[b] = carry + inc - v;
        carry += __shfl(inc, 63);
    }
    if (lane == 0) tot[bin] = carry;
}

// ---------- binscan ----------
__global__ __launch_bounds__(256) void binscan_k(const uint32_t* __restrict__ tot,
                                                 uint32_t* __restrict__ bstart) {
    __shared__ uint32_t part[256];
    const int t = threadIdx.x;
    uint32_t loc[SCH];
    uint32_t s = 0;
#pragma unroll
    for (int j = 0; j < SCH; ++j) {
        int idx = t * SCH + j;
        uint32_t v = (idx < NB) ? tot[idx] : 0;
        loc[j] = s;
        s += v;
    }
    part[t] = s;
    __syncthreads();
    for (int off = 1; off < 256; off <<= 1) {
        uint32_t add = (t >= off) ? part[t - off] : 0;
        __syncthreads();
        part[t] += add;
        __syncthreads();
    }
    uint32_t base = (t > 0) ? part[t - 1] : 0;
#pragma unroll
    for (int j = 0; j < SCH; ++j) {
        int idx = t * SCH + j;
        if (idx < NB) bstart[idx] = base + loc[j];
    }
    if (t == 255) bstart[NB] = part[255];
}

// ---------- scatter: 1024 threads, LDS base staging, no per-edge global table loads ----------
__global__ __launch_bounds__(1024) void scatter_k(const int* __restrict__ ei,
                                                  const float* __restrict__ ea,
                                                  const uint32_t* __restrict__ Bp,
                                                  const uint32_t* __restrict__ bstart,
                                                  uint2* __restrict__ sorted) {
    __shared__ uint32_t cur[NB];                 // 12.5 KB
    __shared__ uint32_t base_[NB];               // 12.5 KB
    const int blk = blockIdx.x;
    for (int i = threadIdx.x; i < NB; i += 1024) {
        cur[i] = 0;
        base_[i] = bstart[i] + Bp[(size_t)i * NBLK + blk];
    }
    __syncthreads();
    const int ebase = blk * EPB;
    for (int j = 0; j < EPB; j += 1024) {
        int e = ebase + j + threadIdx.x;
        if (e < NE) {
            int sn = ei[e];
            int d  = ei[NE + e];
            float a = ea[e];
            int bin = d >> 4;
            uint32_t r = atomicAdd(&cur[bin], 1u);
            uint32_t pos = base_[bin] + r;
            sorted[pos] = make_uint2(__float_as_uint(a),
                                     ((uint32_t)sn << 4) | (uint32_t)(d & 15));
        }
    }
}

// ---------- fused: P+aQ fast path (flag) or G2 fallback; LDS max-agg; epilogue ----------
__global__ __launch_bounds__(256) void fused_k(const uint2* __restrict__ sorted,
                                               const uint32_t* __restrict__ bstart,
                                               const float* __restrict__ w1,
                                               const float* __restrict__ b1,
                                               const float* __restrict__ x,
                                               const uint32_t* __restrict__ PQ,
                                               const uint32_t* __restrict__ xh,
                                               const uint32_t* __restrict__ G2,
                                               const float* __restrict__ root,
                                               const float* __restrict__ bias,
                                               const float* __restrict__ fcw,
                                               const float* __restrict__ fcb,
                                               float* __restrict__ out) {
    __shared__ uint2    ebuf[ECAP];              // 6 KB
    __shared__ uint32_t agg[DPB * ASTR];         // 2.1 KB
    __shared__ float rs[INF_ * OUTF];
    __shared__ float bs[OUTF];
    __shared__ float fws[OUTF * NC];
    __shared__ float fbs[NC];

    const int bin  = blockIdx.x;
    const int segs = (int)bstart[bin];
    const int cnt  = (int)bstart[bin + 1] - segs;
    const int scnt = cnt < ECAP ? cnt : ECAP;

    for (int i = threadIdx.x; i < scnt; i += 256) ebuf[i] = sorted[segs + i];
    for (int i = threadIdx.x; i < DPB * ASTR; i += 256) agg[i] = SENT;
    for (int i = threadIdx.x; i < INF_ * OUTF; i += 256) rs[i] = root[i];
    if (threadIdx.x < OUTF) bs[threadIdx.x] = bias[threadIdx.x];
    for (int i = threadIdx.x; i < OUTF * NC; i += 256) fws[i] = fcw[i];
    if (threadIdx.x < NC) fbs[threadIdx.x] = fcb[threadIdx.x];
    const uint32_t flag = calc_flag(w1, b1);
    __syncthreads();

    const int c   = threadIdx.x & 7;             // channels 4c..4c+3
    const int grp = threadIdx.x >> 3;            // 0..31 edge groups

    if (flag) {
        int it = grp;
        for (; it + 32 < cnt; it += 64) {
            uint2 rA = (it < ECAP) ? ebuf[it] : sorted[segs + it];
            int itB = it + 32;
            uint2 rB = (itB < ECAP) ? ebuf[itB] : sorted[segs + itB];
            float aA = __uint_as_float(rA.x), aB = __uint_as_float(rB.x);
            int sA = rA.y >> 4, sB = rB.y >> 4;
            int dA = rA.y & 15, dB = rB.y & 15;
            const uint2* pA = reinterpret_cast<const uint2*>(PQ + (size_t)sA * 32);
            const uint2* pB = reinterpret_cast<const uint2*>(PQ + (size_t)sB * 32);
            uint2 PuA = pA[c], QuA = pA[8 + c];
            uint2 PuB = pB[c], QuB = pB[8 + c];

            float a0 = fmaf(aA, f16lo(QuA.x), f16lo(PuA.x));
            float a1 = fmaf(aA, f16hi(QuA.x), f16hi(PuA.x));
            float a2 = fmaf(aA, f16lo(QuA.y), f16lo(PuA.y));
            float a3 = fmaf(aA, f16hi(QuA.y), f16hi(PuA.y));
            float b0 = fmaf(aB, f16lo(QuB.x), f16lo(PuB.x));
            float b1v = fmaf(aB, f16hi(QuB.x), f16hi(PuB.x));
            float b2v = fmaf(aB, f16lo(QuB.y), f16lo(PuB.y));
            float b3 = fmaf(aB, f16hi(QuB.y), f16hi(PuB.y));

            uint32_t* agA = &agg[dA * ASTR + c * 4];
            atomicMax(&agA[0], map_f(a0));
            atomicMax(&agA[1], map_f(a1));
            atomicMax(&agA[2], map_f(a2));
            atomicMax(&agA[3], map_f(a3));
            uint32_t* agB = &agg[dB * ASTR + c * 4];
            atomicMax(&agB[0], map_f(b0));
            atomicMax(&agB[1], map_f(b1v));
            atomicMax(&agB[2], map_f(b2v));
            atomicMax(&agB[3], map_f(b3));
        }
        if (it < cnt) {
            uint2 rA = (it < ECAP) ? ebuf[it] : sorted[segs + it];
            float aA = __uint_as_float(rA.x);
            int sA = rA.y >> 4;
            int dA = rA.y & 15;
            const uint2* pA = reinterpret_cast<const uint2*>(PQ + (size_t)sA * 32);
            uint2 PuA = pA[c], QuA = pA[8 + c];
            float a0 = fmaf(aA, f16lo(QuA.x), f16lo(PuA.x));
            float a1 = fmaf(aA, f16hi(QuA.x), f16hi(PuA.x));
            float a2 = fmaf(aA, f16lo(QuA.y), f16lo(PuA.y));
            float a3 = fmaf(aA, f16hi(QuA.y), f16hi(PuA.y));
            uint32_t* agA = &agg[dA * ASTR + c * 4];
            atomicMax(&agA[0], map_f(a0));
            atomicMax(&agA[1], map_f(a1));
            atomicMax(&agA[2], map_f(a2));
            atomicMax(&agA[3], map_f(a3));
        }
    } else {
        for (int it = grp; it < cnt; it += 32) {
            uint2 rec = (it < ECAP) ? ebuf[it] : sorted[segs + it];
            float a = __uint_as_float(rec.x);
            int src = rec.y >> 4;
            int db  = rec.y & 15;
            int q = (int)(a * (float)QG);
            q = q < 0 ? 0 : (q > QG - 1 ? QG - 1 : q);
            const uint4* xp = reinterpret_cast<const uint4*>(xh) + src * 2;
            uint4 hx0 = xp[0];
            uint4 hx1 = xp[1];
            const uint4* gq = reinterpret_cast<const uint4*>(G2) + (size_t)q * 64 + c;
            uint4 g0 = gq[0],  g1 = gq[8],  g2 = gq[16], g3 = gq[24];
            uint4 g4 = gq[32], g5 = gq[40], g6 = gq[48], g7 = gq[56];
            float p0 = 0.f, p1 = 0.f, p2 = 0.f, p3 = 0.f;
            p0 = dot2f(g0.x, hx0.x, p0); p1 = dot2f(g0.y, hx0.x, p1);
            p2 = dot2f(g0.z, hx0.x, p2); p3 = dot2f(g0.w, hx0.x, p3);
            p0 = dot2f(g1.x, hx0.y, p0); p1 = dot2f(g1.y, hx0.y, p1);
            p2 = dot2f(g1.z, hx0.y, p2); p3 = dot2f(g1.w, hx0.y, p3);
            p0 = dot2f(g2.x, hx0.z, p0); p1 = dot2f(g2.y, hx0.z, p1);
            p2 = dot2f(g2.z, hx0.z, p2); p3 = dot2f(g2.w, hx0.z, p3);
            p0 = dot2f(g3.x, hx0.w, p0); p1 = dot2f(g3.y, hx0.w, p1);
            p2 = dot2f(g3.z, hx0.w, p2); p3 = dot2f(g3.w, hx0.w, p3);
            p0 = dot2f(g4.x, hx1.x, p0); p1 = dot2f(g4.y, hx1.x, p1);
            p2 = dot2f(g4.z, hx1.x, p2); p3 = dot2f(g4.w, hx1.x, p3);
            p0 = dot2f(g5.x, hx1.y, p0); p1 = dot2f(g5.y, hx1.y, p1);
            p2 = dot2f(g5.z, hx1.y, p2); p3 = dot2f(g5.w, hx1.y, p3);
            p0 = dot2f(g6.x, hx1.z, p0); p1 = dot2f(g6.y, hx1.z, p1);
            p2 = dot2f(g6.z, hx1.z, p2); p3 = dot2f(g6.w, hx1.z, p3);
            p0 = dot2f(g7.x, hx1.w, p0); p1 = dot2f(g7.y, hx1.w, p1);
            p2 = dot2f(g7.z, hx1.w, p2); p3 = dot2f(g7.w, hx1.w, p3);
            uint32_t* ag = &agg[db * ASTR + c * 4];
            atomicMax(&ag[0], map_f(p0));
            atomicMax(&ag[1], map_f(p1));
            atomicMax(&ag[2], map_f(p2));
            atomicMax(&ag[3], map_f(p3));
        }
    }
    __syncthreads();

    // epilogue: 16 dsts x (8 lanes x 4 channels)
    {
        const int li8 = threadIdx.x & 7;
        const int dl  = threadIdx.x >> 3;
        const int n   = bin * DPB + dl;
        if (dl < DPB && n < NN) {
            const uint32_t* ar = &agg[dl * ASTR + li8 * 4];
            float av[4];
#pragma unroll
            for (int qq = 0; qq < 4; ++qq) {
                uint32_t u = ar[qq];
                av[qq] = (u == SENT) ? 0.f : unmap_f(u);
            }
            const float* xr = x + (size_t)n * INF_;
            float4 xa = *reinterpret_cast<const float4*>(xr);
            float4 xb = *reinterpret_cast<const float4*>(xr + 4);
            float4 xc = *reinterpret_cast<const float4*>(xr + 8);
            float4 xd = *reinterpret_cast<const float4*>(xr + 12);
            float xv[INF_] = {xa.x,xa.y,xa.z,xa.w, xb.x,xb.y,xb.z,xb.w,
                              xc.x,xc.y,xc.z,xc.w, xd.x,xd.y,xd.z,xd.w};
            float ov[4];
#pragma unroll
            for (int qq = 0; qq < 4; ++qq) {
                int oc = li8 * 4 + qq;
                float tv = av[qq] + bs[oc];
#pragma unroll
                for (int i = 0; i < INF_; ++i) tv = fmaf(xv[i], rs[i * OUTF + oc], tv);
                ov[qq] = (tv > 0.f) ? tv : expm1f(tv);   // ELU alpha=1
            }
            float lg[NC];
#pragma unroll
            for (int cc = 0; cc < NC; ++cc) {
                float tv = 0.f;
#pragma unroll
                for (int qq = 0; qq < 4; ++qq) tv = fmaf(ov[qq], fws[(li8 * 4 + qq) * NC + cc], tv);
                lg[cc] = tv;
            }
#pragma unroll
            for (int m = 1; m <= 4; m <<= 1) {
#pragma unroll
                for (int cc = 0; cc < NC; ++cc) lg[cc] += __shfl_xor(lg[cc], m);
            }
#pragma unroll
            for (int cc = 0; cc < NC; ++cc) lg[cc] += fbs[cc];

            float mx = lg[0];
#pragma unroll
            for (int cc = 1; cc < NC; ++cc) mx = fmaxf(mx, lg[cc]);
            float ssum = 0.f;
#pragma unroll
            for (int cc = 0; cc < NC; ++cc) ssum += expf(lg[cc] - mx);
            float lse = mx + logf(ssum);

            float* orow = out + (size_t)n * NC;
            orow[li8] = lg[li8] - lse;
            if (li8 < 2) orow[8 + li8] = lg[8 + li8] - lse;
        }
    }
}

extern "C" void kernel_launch(void* const* d_in, const int* in_sizes, int n_in,
                              void* d_out, int out_size, void* d_ws, size_t ws_size,
                              hipStream_t stream) {
    const float* x    = (const float*)d_in[0];
    const float* ea   = (const float*)d_in[1];
    const int*   ei   = (const int*)d_in[2];
    const float* w1   = (const float*)d_in[3];
    const float* b1   = (const float*)d_in[4];
    const float* w2   = (const float*)d_in[5];
    const float* b2   = (const float*)d_in[6];
    const float* root = (const float*)d_in[7];
    const float* bias = (const float*)d_in[8];
    const float* fcw  = (const float*)d_in[9];
    const float* fcb  = (const float*)d_in[10];
    float* out = (float*)d_out;

    size_t off = 0;
    auto alloc = [&](size_t bytes) {
        void* p = (char*)d_ws + off;
        off += (bytes + 255) & ~(size_t)255;
        return p;
    };
    uint32_t* PQ       = (uint32_t*)alloc((size_t)NN * 32 * 4);                // 6.4 MB
    uint32_t* G2       = (uint32_t*)alloc((size_t)QG * 256 * 4);               // 2 MB (fallback)
    uint32_t* xh       = (uint32_t*)alloc((size_t)NN * INF_ * 2);              // 1.6 MB (fallback)
    uint32_t* H        = (uint32_t*)alloc((size_t)NB * NBLK * 4);              // 2.45 MB
    uint32_t* Bp       = (uint32_t*)alloc((size_t)NB * NBLK * 4);              // 2.45 MB
    uint32_t* tot      = (uint32_t*)alloc((size_t)NB * 4);
    uint32_t* bstart   = (uint32_t*)alloc((size_t)(NB + 1) * 4);
    uint2*    sorted   = (uint2*)alloc((size_t)NE * 8);                        // 6.4 MB

    prep_k<<<GB_PQ + GB_HIST + GB_G2 + GB_XH, 256, 0, stream>>>(
        w1, b1, w2, b2, x, ei, PQ, G2, xh, H);
    colsum_k<<<(NB * 64 + 255) / 256, 256, 0, stream>>>(H, Bp, tot);
    binscan_k<<<1, 256, 0, stream>>>(tot, bstart);
    scatter_k<<<NBLK, 1024, 0, stream>>>(ei, ea, Bp, bstart, sorted);
    fused_k<<<NB, 256, 0, stream>>>(sorted, bstart, w1, b1, x, PQ, xh, G2,
                                    root, bias, fcw, fcb, out);
}

// Round 20
// 76.674 us; speedup vs baseline: 1.2693x; 1.0267x over previous
//
#include <hip/hip_runtime.h>
#include <hip/hip_bf16.h>
#include <stdint.h>

#define NN   50000
#define NE   800000
#define INF_ 16
#define OUTF 32
#define HIDN 25
#define NC   10
#define QG   2048                 // fallback-path quantization levels
#define QPB  16
#define DPB  16                   // dsts per bucket
#define NB   3125                 // 50000/16
#define EPB  4096
#define NBLK 196                  // ceil(NE/EPB)
#define ASTR 33
#define ECAP 768
#define SCH  13                   // ceil(NB/256) (prep-side unused now)
#define SCW  4                    // ceil(NB/1024) for scatter's in-block scan

#define SENT 0x007FFFFFu          // map_f(-inf)

#define GB_PQ   1563              // PQ-prep blocks (32 nodes each)
#define GB_HIST NBLK
#define GB_G2   128               // fallback G2 prep (flag-gated)
#define GB_XH   391               // fallback xh prep (flag-gated)

typedef _Float16 f16x2 __attribute__((ext_vector_type(2)));

__device__ __forceinline__ uint32_t map_f(float f) {
    uint32_t b = __float_as_uint(f);
    return (b & 0x80000000u) ? ~b : (b | 0x80000000u);
}
__device__ __forceinline__ float unmap_f(uint32_t u) {
    return (u & 0x80000000u) ? __uint_as_float(u ^ 0x80000000u)
                             : __uint_as_float(~u);
}
__device__ __forceinline__ float f16lo(uint32_t u) {
    union { uint16_t s; _Float16 h; } v; v.s = (uint16_t)(u & 0xFFFF);
    return (float)v.h;
}
__device__ __forceinline__ float f16hi(uint32_t u) {
    union { uint16_t s; _Float16 h; } v; v.s = (uint16_t)(u >> 16);
    return (float)v.h;
}
__device__ __forceinline__ uint32_t packf16(float a, float b) {
    union { uint32_t u; f16x2 h; } p;
    p.h[0] = (_Float16)a; p.h[1] = (_Float16)b;
    return p.u;
}
__device__ __forceinline__ float dot2f(uint32_t g, uint32_t xb, float acc) {
#if __has_builtin(__builtin_amdgcn_fdot2)
    union { uint32_t u; f16x2 h; } ug, ux;
    ug.u = g; ux.u = xb;
    return __builtin_amdgcn_fdot2(ug.h, ux.h, acc, false);
#else
    return fmaf(f16lo(g), f16lo(xb), fmaf(f16hi(g), f16hi(xb), acc));
#endif
}

// single-segment flag: no ReLU breakpoint strictly inside (0,1). Uniform across threads.
__device__ __forceinline__ uint32_t calc_flag(const float* w1, const float* b1) {
    uint32_t flag = 1;
    for (int k = 0; k < HIDN; ++k) {
        float w = w1[k], b = b1[k];
        if (w != 0.f) {
            float t = -b / w;
            if (t > 0.f && t < 1.f) flag = 0;
        }
    }
    return flag;
}

// ---------- prep: [0,1563) PQ; then hist; then gated G2; then gated xh ----------
__global__ __launch_bounds__(256) void prep_k(const float* __restrict__ w1,
                                              const float* __restrict__ b1,
                                              const float* __restrict__ w2,
                                              const float* __restrict__ b2,
                                              const float* __restrict__ x,
                                              const int* __restrict__ ei,
                                              uint32_t* __restrict__ PQ,
                                              uint32_t* __restrict__ G2,
                                              uint32_t* __restrict__ xh,
                                              uint32_t* __restrict__ H) {
    __shared__ union {
        struct { float ca[512]; float cb[512]; } pq;    // 4 KB
        uint32_t hloc[NB];                              // 12.5 KB
        float hs[QPB][HIDN];                            // 1.6 KB
    } sm;

    const int b = blockIdx.x;
    if (b < GB_PQ) {
        uint32_t mask = 0;
        for (int k = 0; k < HIDN; ++k)
            if (fmaf(0.5f, w1[k], b1[k]) > 0.f) mask |= (1u << k);
        for (int e = threadIdx.x; e < 512; e += 256) {
            float ca = b2[e], cb = 0.f;
            for (int k = 0; k < HIDN; ++k) {
                if ((mask >> k) & 1u) {
                    float wv = w2[k * 512 + e];
                    ca = fmaf(b1[k], wv, ca);
                    cb = fmaf(w1[k], wv, cb);
                }
            }
            sm.pq.ca[e] = ca;
            sm.pq.cb[e] = cb;
        }
        __syncthreads();
        const int c = threadIdx.x & 7;               // channels 4c..4c+3
        const int n = b * 32 + (threadIdx.x >> 3);
        if (n < NN) {
            float xv[INF_];
            const float* xr = x + (size_t)n * INF_;
#pragma unroll
            for (int i = 0; i < INF_; i += 4) {
                float4 v = *reinterpret_cast<const float4*>(xr + i);
                xv[i] = v.x; xv[i+1] = v.y; xv[i+2] = v.z; xv[i+3] = v.w;
            }
            float P[4], Q[4];
#pragma unroll
            for (int j = 0; j < 4; ++j) {
                int o = c * 4 + j;
                float p = 0.f, q = 0.f;
#pragma unroll
                for (int i = 0; i < INF_; ++i) {
                    p = fmaf(xv[i], sm.pq.ca[i * 32 + o], p);
                    q = fmaf(xv[i], sm.pq.cb[i * 32 + o], q);
                }
                P[j] = p; Q[j] = q;
            }
            uint2* row = reinterpret_cast<uint2*>(PQ + (size_t)n * 32);
            row[c]     = make_uint2(packf16(P[0], P[1]), packf16(P[2], P[3]));
            row[8 + c] = make_uint2(packf16(Q[0], Q[1]), packf16(Q[2], Q[3]));
        }
    } else if (b < GB_PQ + GB_HIST) {
        const int blk = b - GB_PQ;
        for (int i = threadIdx.x; i < NB; i += 256) sm.hloc[i] = 0;
        __syncthreads();
        const int base = blk * EPB;
        for (int j = 0; j < EPB; j += 256) {
            int e = base + j + threadIdx.x;
            if (e < NE) atomicAdd(&sm.hloc[ei[NE + e] >> 4], 1u);
        }
        __syncthreads();
        for (int i = threadIdx.x; i < NB; i += 256)
            H[(size_t)i * NBLK + blk] = sm.hloc[i];
    } else if (b < GB_PQ + GB_HIST + GB_G2) {
        if (calc_flag(w1, b1)) return;               // fallback only
        const int gb = b - GB_PQ - GB_HIST;
        for (int i = threadIdx.x; i < QPB * HIDN; i += 256) {
            int qq = i / HIDN, k = i - qq * HIDN;
            float aq = (gb * QPB + qq + 0.5f) * (1.0f / (float)QG);
            sm.hs[qq][k] = fmaxf(fmaf(aq, w1[k], b1[k]), 0.f);
        }
        __syncthreads();
        for (int qq = 0; qq < QPB; ++qq) {
            const int q = gb * QPB + qq;
            int e = threadIdx.x;
            int ip = e >> 5, o = e & 31;
            float g0 = b2[(2 * ip) * OUTF + o];
            float g1 = b2[(2 * ip + 1) * OUTF + o];
#pragma unroll
            for (int k = 0; k < HIDN; ++k) {
                float h = sm.hs[qq][k];
                g0 = fmaf(h, w2[k * 512 + (2 * ip) * OUTF + o], g0);
                g1 = fmaf(h, w2[k * 512 + (2 * ip + 1) * OUTF + o], g1);
            }
            G2[(size_t)q * 256 + e] = packf16(g0, g1);
        }
    } else {
        if (calc_flag(w1, b1)) return;               // fallback only
        int t4 = ((b - GB_PQ - GB_HIST - GB_G2) * 256 + threadIdx.x) * 4;
        if (t4 < NN * INF_ / 2) {
            const float4* xp = reinterpret_cast<const float4*>(x) + (t4 >> 1);
            float4 va = xp[0];
            float4 vb = xp[1];
            xh[t4]     = packf16(va.x, va.y);
            xh[t4 + 1] = packf16(va.z, va.w);
            xh[t4 + 2] = packf16(vb.x, vb.y);
            xh[t4 + 3] = packf16(vb.z, vb.w);
        }
    }
}

// ---------- colsum: wave per bin, prefix over blocks ----------
__global__ __launch_bounds__(256) void colsum_k(const uint32_t* __restrict__ H,
                                                uint32_t* __restrict__ Bp,
                                                uint32_t* __restrict__ tot) {
    const int bin  = (blockIdx.x * 256 + threadIdx.x) >> 6;
    const int lane = threadIdx.x & 63;
    if (bin >= NB) return;
    const uint32_t* hr = H + (size_t)bin * NBLK;
    uint32_t* br = Bp + (size_t)bin * NBLK;
    uint32_t carry = 0;
    for (int b0 = 0; b0 < NBLK; b0 += 64) {
        int b = b0 + lane;
        uint32_t v = (b < NBLK) ? hr[b] : 0;
        uint32_t inc = v;
#pragma unroll
        for (int off = 1; off < 64; off <<= 1) {
            uint32_t t = __shfl_up(inc, off);
            if (lane >= off) inc += t;
        }
        if (b < NBLK) br[b] = carry + inc - v;
        carry += __shfl(inc, 63);
    }
    if (lane == 0) tot[bin] = carry;
}

// ---------- scatter: in-block scan of tot (replaces binscan) + scatter ----------
__global__ __launch_bounds__(1024) void scatter_k(const int* __restrict__ ei,
                                                  const float* __restrict__ ea,
                                                  const uint32_t* __restrict__ Bp,
                                                  const uint32_t* __restrict__ tot,
                                                  uint32_t* __restrict__ bstart,
                                                  uint2* __restrict__ sorted) {
    __shared__ uint32_t cur[NB];                 // 12.5 KB
    __shared__ uint32_t base_[NB];               // 12.5 KB
    __shared__ uint32_t part[1024];              // 4 KB
    const int blk = blockIdx.x;
    const int tid = threadIdx.x;

    // exclusive scan of tot[0..NB) -> bst; base_[bin] = bst + Bp[bin][blk]
    uint32_t loc[SCW];
    uint32_t s = 0;
#pragma unroll
    for (int j = 0; j < SCW; ++j) {
        int idx = tid * SCW + j;
        uint32_t v = (idx < NB) ? tot[idx] : 0;
        loc[j] = s;
        s += v;
    }
    part[tid] = s;
    __syncthreads();
    for (int off = 1; off < 1024; off <<= 1) {
        uint32_t add = (tid >= off) ? part[tid - off] : 0;
        __syncthreads();
        part[tid] += add;
        __syncthreads();
    }
    uint32_t base0 = (tid > 0) ? part[tid - 1] : 0;
#pragma unroll
    for (int j = 0; j < SCW; ++j) {
        int idx = tid * SCW + j;
        if (idx < NB) {
            uint32_t bst = base0 + loc[j];
            base_[idx] = bst + Bp[(size_t)idx * NBLK + blk];
            cur[idx] = 0;
            if (blk == 0) bstart[idx] = bst;     // publish for fused_k
        }
    }
    if (blk == 0 && tid == 1023) bstart[NB] = part[1023];
    __syncthreads();

    const int ebase = blk * EPB;
    for (int j = 0; j < EPB; j += 1024) {
        int e = ebase + j + tid;
        if (e < NE) {
            int sn = ei[e];
            int d  = ei[NE + e];
            float a = ea[e];
            int bin = d >> 4;
            uint32_t r = atomicAdd(&cur[bin], 1u);
            uint32_t pos = base_[bin] + r;
            sorted[pos] = make_uint2(__float_as_uint(a),
                                     ((uint32_t)sn << 4) | (uint32_t)(d & 15));
        }
    }
}

// ---------- fused: P+aQ fast path (flag) or G2 fallback; LDS max-agg; epilogue ----------
__global__ __launch_bounds__(256) void fused_k(const uint2* __restrict__ sorted,
                                               const uint32_t* __restrict__ bstart,
                                               const float* __restrict__ w1,
                                               const float* __restrict__ b1,
                                               const float* __restrict__ x,
                                               const uint32_t* __restrict__ PQ,
                                               const uint32_t* __restrict__ xh,
                                               const uint32_t* __restrict__ G2,
                                               const float* __restrict__ root,
                                               const float* __restrict__ bias,
                                               const float* __restrict__ fcw,
                                               const float* __restrict__ fcb,
                                               float* __restrict__ out) {
    __shared__ uint2    ebuf[ECAP];              // 6 KB
    __shared__ uint32_t agg[DPB * ASTR];         // 2.1 KB
    __shared__ float rs[INF_ * OUTF];
    __shared__ float bs[OUTF];
    __shared__ float fws[OUTF * NC];
    __shared__ float fbs[NC];

    const int bin  = blockIdx.x;
    const int segs = (int)bstart[bin];
    const int cnt  = (int)bstart[bin + 1] - segs;
    const int scnt = cnt < ECAP ? cnt : ECAP;

    for (int i = threadIdx.x; i < scnt; i += 256) ebuf[i] = sorted[segs + i];
    for (int i = threadIdx.x; i < DPB * ASTR; i += 256) agg[i] = SENT;
    for (int i = threadIdx.x; i < INF_ * OUTF; i += 256) rs[i] = root[i];
    if (threadIdx.x < OUTF) bs[threadIdx.x] = bias[threadIdx.x];
    for (int i = threadIdx.x; i < OUTF * NC; i += 256) fws[i] = fcw[i];
    if (threadIdx.x < NC) fbs[threadIdx.x] = fcb[threadIdx.x];
    const uint32_t flag = calc_flag(w1, b1);
    __syncthreads();

    const int c   = threadIdx.x & 7;             // channels 4c..4c+3
    const int grp = threadIdx.x >> 3;            // 0..31 edge groups

    if (flag) {
        int it = grp;
        for (; it + 32 < cnt; it += 64) {
            uint2 rA = (it < ECAP) ? ebuf[it] : sorted[segs + it];
            int itB = it + 32;
            uint2 rB = (itB < ECAP) ? ebuf[itB] : sorted[segs + itB];
            float aA = __uint_as_float(rA.x), aB = __uint_as_float(rB.x);
            int sA = rA.y >> 4, sB = rB.y >> 4;
            int dA = rA.y & 15, dB = rB.y & 15;
            const uint2* pA = reinterpret_cast<const uint2*>(PQ + (size_t)sA * 32);
            const uint2* pB = reinterpret_cast<const uint2*>(PQ + (size_t)sB * 32);
            uint2 PuA = pA[c], QuA = pA[8 + c];
            uint2 PuB = pB[c], QuB = pB[8 + c];

            float a0 = fmaf(aA, f16lo(QuA.x), f16lo(PuA.x));
            float a1 = fmaf(aA, f16hi(QuA.x), f16hi(PuA.x));
            float a2 = fmaf(aA, f16lo(QuA.y), f16lo(PuA.y));
            float a3 = fmaf(aA, f16hi(QuA.y), f16hi(PuA.y));
            float b0 = fmaf(aB, f16lo(QuB.x), f16lo(PuB.x));
            float b1v = fmaf(aB, f16hi(QuB.x), f16hi(PuB.x));
            float b2v = fmaf(aB, f16lo(QuB.y), f16lo(PuB.y));
            float b3 = fmaf(aB, f16hi(QuB.y), f16hi(PuB.y));

            uint32_t* agA = &agg[dA * ASTR + c * 4];
            atomicMax(&agA[0], map_f(a0));
            atomicMax(&agA[1], map_f(a1));
            atomicMax(&agA[2], map_f(a2));
            atomicMax(&agA[3], map_f(a3));
            uint32_t* agB = &agg[dB * ASTR + c * 4];
            atomicMax(&agB[0], map_f(b0));
            atomicMax(&agB[1], map_f(b1v));
            atomicMax(&agB[2], map_f(b2v));
            atomicMax(&agB[3], map_f(b3));
        }
        if (it < cnt) {
            uint2 rA = (it < ECAP) ? ebuf[it] : sorted[segs + it];
            float aA = __uint_as_float(rA.x);
            int sA = rA.y >> 4;
            int dA = rA.y & 15;
            const uint2* pA = reinterpret_cast<const uint2*>(PQ + (size_t)sA * 32);
            uint2 PuA = pA[c], QuA = pA[8 + c];
            float a0 = fmaf(aA, f16lo(QuA.x), f16lo(PuA.x));
            float a1 = fmaf(aA, f16hi(QuA.x), f16hi(PuA.x));
            float a2 = fmaf(aA, f16lo(QuA.y), f16lo(PuA.y));
            float a3 = fmaf(aA, f16hi(QuA.y), f16hi(PuA.y));
            uint32_t* agA = &agg[dA * ASTR + c * 4];
            atomicMax(&agA[0], map_f(a0));
            atomicMax(&agA[1], map_f(a1));
            atomicMax(&agA[2], map_f(a2));
            atomicMax(&agA[3], map_f(a3));
        }
    } else {
        for (int it = grp; it < cnt; it += 32) {
            uint2 rec = (it < ECAP) ? ebuf[it] : sorted[segs + it];
            float a = __uint_as_float(rec.x);
            int src = rec.y >> 4;
            int db  = rec.y & 15;
            int q = (int)(a * (float)QG);
            q = q < 0 ? 0 : (q > QG - 1 ? QG - 1 : q);
            const uint4* xp = reinterpret_cast<const uint4*>(xh) + src * 2;
            uint4 hx0 = xp[0];
            uint4 hx1 = xp[1];
            const uint4* gq = reinterpret_cast<const uint4*>(G2) + (size_t)q * 64 + c;
            uint4 g0 = gq[0],  g1 = gq[8],  g2 = gq[16], g3 = gq[24];
            uint4 g4 = gq[32], g5 = gq[40], g6 = gq[48], g7 = gq[56];
            float p0 = 0.f, p1 = 0.f, p2 = 0.f, p3 = 0.f;
            p0 = dot2f(g0.x, hx0.x, p0); p1 = dot2f(g0.y, hx0.x, p1);
            p2 = dot2f(g0.z, hx0.x, p2); p3 = dot2f(g0.w, hx0.x, p3);
            p0 = dot2f(g1.x, hx0.y, p0); p1 = dot2f(g1.y, hx0.y, p1);
            p2 = dot2f(g1.z, hx0.y, p2); p3 = dot2f(g1.w, hx0.y, p3);
            p0 = dot2f(g2.x, hx0.z, p0); p1 = dot2f(g2.y, hx0.z, p1);
            p2 = dot2f(g2.z, hx0.z, p2); p3 = dot2f(g2.w, hx0.z, p3);
            p0 = dot2f(g3.x, hx0.w, p0); p1 = dot2f(g3.y, hx0.w, p1);
            p2 = dot2f(g3.z, hx0.w, p2); p3 = dot2f(g3.w, hx0.w, p3);
            p0 = dot2f(g4.x, hx1.x, p0); p1 = dot2f(g4.y, hx1.x, p1);
            p2 = dot2f(g4.z, hx1.x, p2); p3 = dot2f(g4.w, hx1.x, p3);
            p0 = dot2f(g5.x, hx1.y, p0); p1 = dot2f(g5.y, hx1.y, p1);
            p2 = dot2f(g5.z, hx1.y, p2); p3 = dot2f(g5.w, hx1.y, p3);
            p0 = dot2f(g6.x, hx1.z, p0); p1 = dot2f(g6.y, hx1.z, p1);
            p2 = dot2f(g6.z, hx1.z, p2); p3 = dot2f(g6.w, hx1.z, p3);
            p0 = dot2f(g7.x, hx1.w, p0); p1 = dot2f(g7.y, hx1.w, p1);
            p2 = dot2f(g7.z, hx1.w, p2); p3 = dot2f(g7.w, hx1.w, p3);
            uint32_t* ag = &agg[db * ASTR + c * 4];
            atomicMax(&ag[0], map_f(p0));
            atomicMax(&ag[1], map_f(p1));
            atomicMax(&ag[2], map_f(p2));
            atomicMax(&ag[3], map_f(p3));
        }
    }
    __syncthreads();

    // epilogue: 16 dsts x (8 lanes x 4 channels)
    {
        const int li8 = threadIdx.x & 7;
        const int dl  = threadIdx.x >> 3;
        const int n   = bin * DPB + dl;
        if (dl < DPB && n < NN) {
            const uint32_t* ar = &agg[dl * ASTR + li8 * 4];
            float av[4];
#pragma unroll
            for (int qq = 0; qq < 4; ++qq) {
                uint32_t u = ar[qq];
                av[qq] = (u == SENT) ? 0.f : unmap_f(u);
            }
            const float* xr = x + (size_t)n * INF_;
            float4 xa = *reinterpret_cast<const float4*>(xr);
            float4 xb = *reinterpret_cast<const float4*>(xr + 4);
            float4 xc = *reinterpret_cast<const float4*>(xr + 8);
            float4 xd = *reinterpret_cast<const float4*>(xr + 12);
            float xv[INF_] = {xa.x,xa.y,xa.z,xa.w, xb.x,xb.y,xb.z,xb.w,
                              xc.x,xc.y,xc.z,xc.w, xd.x,xd.y,xd.z,xd.w};
            float ov[4];
#pragma unroll
            for (int qq = 0; qq < 4; ++qq) {
                int oc = li8 * 4 + qq;
                float tv = av[qq] + bs[oc];
#pragma unroll
                for (int i = 0; i < INF_; ++i) tv = fmaf(xv[i], rs[i * OUTF + oc], tv);
                ov[qq] = (tv > 0.f) ? tv : expm1f(tv);   // ELU alpha=1
            }
            float lg[NC];
#pragma unroll
            for (int cc = 0; cc < NC; ++cc) {
                float tv = 0.f;
#pragma unroll
                for (int qq = 0; qq < 4; ++qq) tv = fmaf(ov[qq], fws[(li8 * 4 + qq) * NC + cc], tv);
                lg[cc] = tv;
            }
#pragma unroll
            for (int m = 1; m <= 4; m <<= 1) {
#pragma unroll
                for (int cc = 0; cc < NC; ++cc) lg[cc] += __shfl_xor(lg[cc], m);
            }
#pragma unroll
            for (int cc = 0; cc < NC; ++cc) lg[cc] += fbs[cc];

            float mx = lg[0];
#pragma unroll
            for (int cc = 1; cc < NC; ++cc) mx = fmaxf(mx, lg[cc]);
            float ssum = 0.f;
#pragma unroll
            for (int cc = 0; cc < NC; ++cc) ssum += expf(lg[cc] - mx);
            float lse = mx + logf(ssum);

            float* orow = out + (size_t)n * NC;
            orow[li8] = lg[li8] - lse;
            if (li8 < 2) orow[8 + li8] = lg[8 + li8] - lse;
        }
    }
}

extern "C" void kernel_launch(void* const* d_in, const int* in_sizes, int n_in,
                              void* d_out, int out_size, void* d_ws, size_t ws_size,
                              hipStream_t stream) {
    const float* x    = (const float*)d_in[0];
    const float* ea   = (const float*)d_in[1];
    const int*   ei   = (const int*)d_in[2];
    const float* w1   = (const float*)d_in[3];
    const float* b1   = (const float*)d_in[4];
    const float* w2   = (const float*)d_in[5];
    const float* b2   = (const float*)d_in[6];
    const float* root = (const float*)d_in[7];
    const float* bias = (const float*)d_in[8];
    const float* fcw  = (const float*)d_in[9];
    const float* fcb  = (const float*)d_in[10];
    float* out = (float*)d_out;

    size_t off = 0;
    auto alloc = [&](size_t bytes) {
        void* p = (char*)d_ws + off;
        off += (bytes + 255) & ~(size_t)255;
        return p;
    };
    uint32_t* PQ       = (uint32_t*)alloc((size_t)NN * 32 * 4);                // 6.4 MB
    uint32_t* G2       = (uint32_t*)alloc((size_t)QG * 256 * 4);               // 2 MB (fallback)
    uint32_t* xh       = (uint32_t*)alloc((size_t)NN * INF_ * 2);              // 1.6 MB (fallback)
    uint32_t* H        = (uint32_t*)alloc((size_t)NB * NBLK * 4);              // 2.45 MB
    uint32_t* Bp       = (uint32_t*)alloc((size_t)NB * NBLK * 4);              // 2.45 MB
    uint32_t* tot      = (uint32_t*)alloc((size_t)NB * 4);
    uint32_t* bstart   = (uint32_t*)alloc((size_t)(NB + 1) * 4);
    uint2*    sorted   = (uint2*)alloc((size_t)NE * 8);                        // 6.4 MB

    prep_k<<<GB_PQ + GB_HIST + GB_G2 + GB_XH, 256, 0, stream>>>(
        w1, b1, w2, b2, x, ei, PQ, G2, xh, H);
    colsum_k<<<(NB * 64 + 255) / 256, 256, 0, stream>>>(H, Bp, tot);
    scatter_k<<<NBLK, 1024, 0, stream>>>(ei, ea, Bp, tot, bstart, sorted);
    fused_k<<<NB, 256, 0, stream>>>(sorted, bstart, w1, b1, x, PQ, xh, G2,
                                    root, bias, fcw, fcb, out);
}

// Round 21
// 75.203 us; speedup vs baseline: 1.2941x; 1.0196x over previous
//
#include <hip/hip_runtime.h>
#include <hip/hip_bf16.h>
#include <stdint.h>

#define NN   50000
#define NE   800000
#define INF_ 16
#define OUTF 32
#define HIDN 25
#define NC   10
#define QG   2048                 // fallback-path quantization levels
#define QPB  16
#define DPB  16                   // dsts per bucket
#define NB   3125                 // 50000/16
#define EPB  4096
#define NBLK 196                  // ceil(NE/EPB)
#define ASTR 33
#define SCW  4                    // ceil(NB/1024) for scatter's in-block scan

#define SENT 0x007FFFFFu          // map_f(-inf)

#define GB_PQ   1563              // PQ-prep blocks (32 nodes each)
#define GB_HIST NBLK
#define GB_G2   128               // fallback G2 prep (flag-gated)
#define GB_XH   391               // fallback xh prep (flag-gated)

typedef _Float16 f16x2 __attribute__((ext_vector_type(2)));

__device__ __forceinline__ uint32_t map_f(float f) {
    uint32_t b = __float_as_uint(f);
    return (b & 0x80000000u) ? ~b : (b | 0x80000000u);
}
__device__ __forceinline__ float unmap_f(uint32_t u) {
    return (u & 0x80000000u) ? __uint_as_float(u ^ 0x80000000u)
                             : __uint_as_float(~u);
}
__device__ __forceinline__ float f16lo(uint32_t u) {
    union { uint16_t s; _Float16 h; } v; v.s = (uint16_t)(u & 0xFFFF);
    return (float)v.h;
}
__device__ __forceinline__ float f16hi(uint32_t u) {
    union { uint16_t s; _Float16 h; } v; v.s = (uint16_t)(u >> 16);
    return (float)v.h;
}
__device__ __forceinline__ uint32_t packf16(float a, float b) {
    union { uint32_t u; f16x2 h; } p;
    p.h[0] = (_Float16)a; p.h[1] = (_Float16)b;
    return p.u;
}
__device__ __forceinline__ float dot2f(uint32_t g, uint32_t xb, float acc) {
#if __has_builtin(__builtin_amdgcn_fdot2)
    union { uint32_t u; f16x2 h; } ug, ux;
    ug.u = g; ux.u = xb;
    return __builtin_amdgcn_fdot2(ug.h, ux.h, acc, false);
#else
    return fmaf(f16lo(g), f16lo(xb), fmaf(f16hi(g), f16hi(xb), acc));
#endif
}

// single-segment flag: no ReLU breakpoint strictly inside (0,1). Uniform across threads.
__device__ __forceinline__ uint32_t calc_flag(const float* w1, const float* b1) {
    uint32_t flag = 1;
    for (int k = 0; k < HIDN; ++k) {
        float w = w1[k], b = b1[k];
        if (w != 0.f) {
            float t = -b / w;
            if (t > 0.f && t < 1.f) flag = 0;
        }
    }
    return flag;
}

// ---------- prep: [0,1563) PQ; then hist (u16 H); then gated G2; then gated xh ----------
__global__ __launch_bounds__(256) void prep_k(const float* __restrict__ w1,
                                              const float* __restrict__ b1,
                                              const float* __restrict__ w2,
                                              const float* __restrict__ b2,
                                              const float* __restrict__ x,
                                              const int* __restrict__ ei,
                                              uint32_t* __restrict__ PQ,
                                              uint32_t* __restrict__ G2,
                                              uint32_t* __restrict__ xh,
                                              uint16_t* __restrict__ H) {
    __shared__ union {
        struct { float ca[512]; float cb[512]; } pq;    // 4 KB
        uint32_t hloc[NB];                              // 12.5 KB
        float hs[QPB][HIDN];                            // 1.6 KB
    } sm;

    const int b = blockIdx.x;
    if (b < GB_PQ) {
        uint32_t mask = 0;
        for (int k = 0; k < HIDN; ++k)
            if (fmaf(0.5f, w1[k], b1[k]) > 0.f) mask |= (1u << k);
        for (int e = threadIdx.x; e < 512; e += 256) {
            float ca = b2[e], cb = 0.f;
            for (int k = 0; k < HIDN; ++k) {
                if ((mask >> k) & 1u) {
                    float wv = w2[k * 512 + e];
                    ca = fmaf(b1[k], wv, ca);
                    cb = fmaf(w1[k], wv, cb);
                }
            }
            sm.pq.ca[e] = ca;
            sm.pq.cb[e] = cb;
        }
        __syncthreads();
        const int c = threadIdx.x & 7;               // channels 4c..4c+3
        const int n = b * 32 + (threadIdx.x >> 3);
        if (n < NN) {
            float xv[INF_];
            const float* xr = x + (size_t)n * INF_;
#pragma unroll
            for (int i = 0; i < INF_; i += 4) {
                float4 v = *reinterpret_cast<const float4*>(xr + i);
                xv[i] = v.x; xv[i+1] = v.y; xv[i+2] = v.z; xv[i+3] = v.w;
            }
            float P[4], Q[4];
#pragma unroll
            for (int j = 0; j < 4; ++j) {
                int o = c * 4 + j;
                float p = 0.f, q = 0.f;
#pragma unroll
                for (int i = 0; i < INF_; ++i) {
                    p = fmaf(xv[i], sm.pq.ca[i * 32 + o], p);
                    q = fmaf(xv[i], sm.pq.cb[i * 32 + o], q);
                }
                P[j] = p; Q[j] = q;
            }
            uint2* row = reinterpret_cast<uint2*>(PQ + (size_t)n * 32);
            row[c]     = make_uint2(packf16(P[0], P[1]), packf16(P[2], P[3]));
            row[8 + c] = make_uint2(packf16(Q[0], Q[1]), packf16(Q[2], Q[3]));
        }
    } else if (b < GB_PQ + GB_HIST) {
        const int blk = b - GB_PQ;
        for (int i = threadIdx.x; i < NB; i += 256) sm.hloc[i] = 0;
        __syncthreads();
        const int base = blk * EPB;
        for (int j = 0; j < EPB; j += 256) {
            int e = base + j + threadIdx.x;
            if (e < NE) atomicAdd(&sm.hloc[ei[NE + e] >> 4], 1u);
        }
        __syncthreads();
        for (int i = threadIdx.x; i < NB; i += 256)
            H[(size_t)i * NBLK + blk] = (uint16_t)sm.hloc[i];
    } else if (b < GB_PQ + GB_HIST + GB_G2) {
        if (calc_flag(w1, b1)) return;               // fallback only
        const int gb = b - GB_PQ - GB_HIST;
        for (int i = threadIdx.x; i < QPB * HIDN; i += 256) {
            int qq = i / HIDN, k = i - qq * HIDN;
            float aq = (gb * QPB + qq + 0.5f) * (1.0f / (float)QG);
            sm.hs[qq][k] = fmaxf(fmaf(aq, w1[k], b1[k]), 0.f);
        }
        __syncthreads();
        for (int qq = 0; qq < QPB; ++qq) {
            const int q = gb * QPB + qq;
            int e = threadIdx.x;
            int ip = e >> 5, o = e & 31;
            float g0 = b2[(2 * ip) * OUTF + o];
            float g1 = b2[(2 * ip + 1) * OUTF + o];
#pragma unroll
            for (int k = 0; k < HIDN; ++k) {
                float h = sm.hs[qq][k];
                g0 = fmaf(h, w2[k * 512 + (2 * ip) * OUTF + o], g0);
                g1 = fmaf(h, w2[k * 512 + (2 * ip + 1) * OUTF + o], g1);
            }
            G2[(size_t)q * 256 + e] = packf16(g0, g1);
        }
    } else {
        if (calc_flag(w1, b1)) return;               // fallback only
        int t4 = ((b - GB_PQ - GB_HIST - GB_G2) * 256 + threadIdx.x) * 4;
        if (t4 < NN * INF_ / 2) {
            const float4* xp = reinterpret_cast<const float4*>(x) + (t4 >> 1);
            float4 va = xp[0];
            float4 vb = xp[1];
            xh[t4]     = packf16(va.x, va.y);
            xh[t4 + 1] = packf16(va.z, va.w);
            xh[t4 + 2] = packf16(vb.x, vb.y);
            xh[t4 + 3] = packf16(vb.z, vb.w);
        }
    }
}

// ---------- colsum: wave per bin, prefix over blocks (u16 H -> u16 Bp, u32 tot) ----------
__global__ __launch_bounds__(256) void colsum_k(const uint16_t* __restrict__ H,
                                                uint16_t* __restrict__ Bp,
                                                uint32_t* __restrict__ tot) {
    const int bin  = (blockIdx.x * 256 + threadIdx.x) >> 6;
    const int lane = threadIdx.x & 63;
    if (bin >= NB) return;
    const uint16_t* hr = H + (size_t)bin * NBLK;
    uint16_t* br = Bp + (size_t)bin * NBLK;
    uint32_t carry = 0;
    for (int b0 = 0; b0 < NBLK; b0 += 64) {
        int b = b0 + lane;
        uint32_t v = (b < NBLK) ? (uint32_t)hr[b] : 0;
        uint32_t inc = v;
#pragma unroll
        for (int off = 1; off < 64; off <<= 1) {
            uint32_t t = __shfl_up(inc, off);
            if (lane >= off) inc += t;
        }
        if (b < NBLK) br[b] = (uint16_t)(carry + inc - v);
        carry += __shfl(inc, 63);
    }
    if (lane == 0) tot[bin] = carry;
}

// ---------- scatter: in-block scan of tot + Bp-offset bases + scatter ----------
__global__ __launch_bounds__(1024) void scatter_k(const int* __restrict__ ei,
                                                  const float* __restrict__ ea,
                                                  const uint16_t* __restrict__ Bp,
                                                  const uint32_t* __restrict__ tot,
                                                  uint32_t* __restrict__ bstart,
                                                  uint2* __restrict__ sorted) {
    __shared__ uint32_t cur[NB];                 // 12.5 KB
    __shared__ uint32_t base_[NB];               // 12.5 KB
    __shared__ uint32_t part[1024];              // 4 KB
    const int blk = blockIdx.x;
    const int tid = threadIdx.x;

    uint32_t loc[SCW];
    uint32_t s = 0;
#pragma unroll
    for (int j = 0; j < SCW; ++j) {
        int idx = tid * SCW + j;
        uint32_t v = (idx < NB) ? tot[idx] : 0;
        loc[j] = s;
        s += v;
    }
    part[tid] = s;
    __syncthreads();
    for (int off = 1; off < 1024; off <<= 1) {
        uint32_t add = (tid >= off) ? part[tid - off] : 0;
        __syncthreads();
        part[tid] += add;
        __syncthreads();
    }
    uint32_t base0 = (tid > 0) ? part[tid - 1] : 0;
#pragma unroll
    for (int j = 0; j < SCW; ++j) {
        int idx = tid * SCW + j;
        if (idx < NB) {
            uint32_t bst = base0 + loc[j];
            base_[idx] = bst + (uint32_t)Bp[(size_t)idx * NBLK + blk];
            cur[idx] = 0;
            if (blk == 0) bstart[idx] = bst;     // publish for fused_k
        }
    }
    if (blk == 0 && tid == 1023) bstart[NB] = part[1023];
    __syncthreads();

    const int ebase = blk * EPB;
    for (int j = 0; j < EPB; j += 1024) {
        int e = ebase + j + tid;
        if (e < NE) {
            int sn = ei[e];
            int d  = ei[NE + e];
            float a = ea[e];
            int bin = d >> 4;
            uint32_t r = atomicAdd(&cur[bin], 1u);
            uint32_t pos = base_[bin] + r;
            sorted[pos] = make_uint2(__float_as_uint(a),
                                     ((uint32_t)sn << 4) | (uint32_t)(d & 15));
        }
    }
}

// ---------- fused: P+aQ fast path (flag) or G2 fallback; no staging; LDS max-agg ----------
__global__ __launch_bounds__(256) void fused_k(const uint2* __restrict__ sorted,
                                               const uint32_t* __restrict__ bstart,
                                               const float* __restrict__ w1,
                                               const float* __restrict__ b1,
                                               const float* __restrict__ x,
                                               const uint32_t* __restrict__ PQ,
                                               const uint32_t* __restrict__ xh,
                                               const uint32_t* __restrict__ G2,
                                               const float* __restrict__ root,
                                               const float* __restrict__ bias,
                                               const float* __restrict__ fcw,
                                               const float* __restrict__ fcb,
                                               float* __restrict__ out) {
    __shared__ uint32_t agg[DPB * ASTR];         // 2.1 KB
    __shared__ float rs[INF_ * OUTF];
    __shared__ float bs[OUTF];
    __shared__ float fws[OUTF * NC];
    __shared__ float fbs[NC];

    const int bin  = blockIdx.x;
    const int segs = (int)bstart[bin];
    const int cnt  = (int)bstart[bin + 1] - segs;
    const uint2* seg = sorted + segs;

    for (int i = threadIdx.x; i < DPB * ASTR; i += 256) agg[i] = SENT;
    for (int i = threadIdx.x; i < INF_ * OUTF; i += 256) rs[i] = root[i];
    if (threadIdx.x < OUTF) bs[threadIdx.x] = bias[threadIdx.x];
    for (int i = threadIdx.x; i < OUTF * NC; i += 256) fws[i] = fcw[i];
    if (threadIdx.x < NC) fbs[threadIdx.x] = fcb[threadIdx.x];
    const uint32_t flag = calc_flag(w1, b1);
    __syncthreads();

    const int c   = threadIdx.x & 7;             // channels 4c..4c+3
    const int grp = threadIdx.x >> 3;            // 0..31 edge groups

    if (flag) {
        int it = grp;
        for (; it + 32 < cnt; it += 64) {
            uint2 rA = seg[it];
            uint2 rB = seg[it + 32];
            float aA = __uint_as_float(rA.x), aB = __uint_as_float(rB.x);
            int sA = rA.y >> 4, sB = rB.y >> 4;
            int dA = rA.y & 15, dB = rB.y & 15;
            const uint2* pA = reinterpret_cast<const uint2*>(PQ + (size_t)sA * 32);
            const uint2* pB = reinterpret_cast<const uint2*>(PQ + (size_t)sB * 32);
            uint2 PuA = pA[c], QuA = pA[8 + c];
            uint2 PuB = pB[c], QuB = pB[8 + c];

            float a0 = fmaf(aA, f16lo(QuA.x), f16lo(PuA.x));
            float a1 = fmaf(aA, f16hi(QuA.x), f16hi(PuA.x));
            float a2 = fmaf(aA, f16lo(QuA.y), f16lo(PuA.y));
            float a3 = fmaf(aA, f16hi(QuA.y), f16hi(PuA.y));
            float b0 = fmaf(aB, f16lo(QuB.x), f16lo(PuB.x));
            float b1v = fmaf(aB, f16hi(QuB.x), f16hi(PuB.x));
            float b2v = fmaf(aB, f16lo(QuB.y), f16lo(PuB.y));
            float b3 = fmaf(aB, f16hi(QuB.y), f16hi(PuB.y));

            uint32_t* agA = &agg[dA * ASTR + c * 4];
            atomicMax(&agA[0], map_f(a0));
            atomicMax(&agA[1], map_f(a1));
            atomicMax(&agA[2], map_f(a2));
            atomicMax(&agA[3], map_f(a3));
            uint32_t* agB = &agg[dB * ASTR + c * 4];
            atomicMax(&agB[0], map_f(b0));
            atomicMax(&agB[1], map_f(b1v));
            atomicMax(&agB[2], map_f(b2v));
            atomicMax(&agB[3], map_f(b3));
        }
        if (it < cnt) {
            uint2 rA = seg[it];
            float aA = __uint_as_float(rA.x);
            int sA = rA.y >> 4;
            int dA = rA.y & 15;
            const uint2* pA = reinterpret_cast<const uint2*>(PQ + (size_t)sA * 32);
            uint2 PuA = pA[c], QuA = pA[8 + c];
            float a0 = fmaf(aA, f16lo(QuA.x), f16lo(PuA.x));
            float a1 = fmaf(aA, f16hi(QuA.x), f16hi(PuA.x));
            float a2 = fmaf(aA, f16lo(QuA.y), f16lo(PuA.y));
            float a3 = fmaf(aA, f16hi(QuA.y), f16hi(PuA.y));
            uint32_t* agA = &agg[dA * ASTR + c * 4];
            atomicMax(&agA[0], map_f(a0));
            atomicMax(&agA[1], map_f(a1));
            atomicMax(&agA[2], map_f(a2));
            atomicMax(&agA[3], map_f(a3));
        }
    } else {
        for (int it = grp; it < cnt; it += 32) {
            uint2 rec = seg[it];
            float a = __uint_as_float(rec.x);
            int src = rec.y >> 4;
            int db  = rec.y & 15;
            int q = (int)(a * (float)QG);
            q = q < 0 ? 0 : (q > QG - 1 ? QG - 1 : q);
            const uint4* xp = reinterpret_cast<const uint4*>(xh) + src * 2;
            uint4 hx0 = xp[0];
            uint4 hx1 = xp[1];
            const uint4* gq = reinterpret_cast<const uint4*>(G2) + (size_t)q * 64 + c;
            uint4 g0 = gq[0],  g1 = gq[8],  g2 = gq[16], g3 = gq[24];
            uint4 g4 = gq[32], g5 = gq[40], g6 = gq[48], g7 = gq[56];
            float p0 = 0.f, p1 = 0.f, p2 = 0.f, p3 = 0.f;
            p0 = dot2f(g0.x, hx0.x, p0); p1 = dot2f(g0.y, hx0.x, p1);
            p2 = dot2f(g0.z, hx0.x, p2); p3 = dot2f(g0.w, hx0.x, p3);
            p0 = dot2f(g1.x, hx0.y, p0); p1 = dot2f(g1.y, hx0.y, p1);
            p2 = dot2f(g1.z, hx0.y, p2); p3 = dot2f(g1.w, hx0.y, p3);
            p0 = dot2f(g2.x, hx0.z, p0); p1 = dot2f(g2.y, hx0.z, p1);
            p2 = dot2f(g2.z, hx0.z, p2); p3 = dot2f(g2.w, hx0.z, p3);
            p0 = dot2f(g3.x, hx0.w, p0); p1 = dot2f(g3.y, hx0.w, p1);
            p2 = dot2f(g3.z, hx0.w, p2); p3 = dot2f(g3.w, hx0.w, p3);
            p0 = dot2f(g4.x, hx1.x, p0); p1 = dot2f(g4.y, hx1.x, p1);
            p2 = dot2f(g4.z, hx1.x, p2); p3 = dot2f(g4.w, hx1.x, p3);
            p0 = dot2f(g5.x, hx1.y, p0); p1 = dot2f(g5.y, hx1.y, p1);
            p2 = dot2f(g5.z, hx1.y, p2); p3 = dot2f(g5.w, hx1.y, p3);
            p0 = dot2f(g6.x, hx1.z, p0); p1 = dot2f(g6.y, hx1.z, p1);
            p2 = dot2f(g6.z, hx1.z, p2); p3 = dot2f(g6.w, hx1.z, p3);
            p0 = dot2f(g7.x, hx1.w, p0); p1 = dot2f(g7.y, hx1.w, p1);
            p2 = dot2f(g7.z, hx1.w, p2); p3 = dot2f(g7.w, hx1.w, p3);
            uint32_t* ag = &agg[db * ASTR + c * 4];
            atomicMax(&ag[0], map_f(p0));
            atomicMax(&ag[1], map_f(p1));
            atomicMax(&ag[2], map_f(p2));
            atomicMax(&ag[3], map_f(p3));
        }
    }
    __syncthreads();

    // epilogue: 16 dsts x (8 lanes x 4 channels)
    {
        const int li8 = threadIdx.x & 7;
        const int dl  = threadIdx.x >> 3;
        const int n   = bin * DPB + dl;
        if (dl < DPB && n < NN) {
            const uint32_t* ar = &agg[dl * ASTR + li8 * 4];
            float av[4];
#pragma unroll
            for (int qq = 0; qq < 4; ++qq) {
                uint32_t u = ar[qq];
                av[qq] = (u == SENT) ? 0.f : unmap_f(u);
            }
            const float* xr = x + (size_t)n * INF_;
            float4 xa = *reinterpret_cast<const float4*>(xr);
            float4 xb = *reinterpret_cast<const float4*>(xr + 4);
            float4 xc = *reinterpret_cast<const float4*>(xr + 8);
            float4 xd = *reinterpret_cast<const float4*>(xr + 12);
            float xv[INF_] = {xa.x,xa.y,xa.z,xa.w, xb.x,xb.y,xb.z,xb.w,
                              xc.x,xc.y,xc.z,xc.w, xd.x,xd.y,xd.z,xd.w};
            float ov[4];
#pragma unroll
            for (int qq = 0; qq < 4; ++qq) {
                int oc = li8 * 4 + qq;
                float tv = av[qq] + bs[oc];
#pragma unroll
                for (int i = 0; i < INF_; ++i) tv = fmaf(xv[i], rs[i * OUTF + oc], tv);
                ov[qq] = (tv > 0.f) ? tv : expm1f(tv);   // ELU alpha=1
            }
            float lg[NC];
#pragma unroll
            for (int cc = 0; cc < NC; ++cc) {
                float tv = 0.f;
#pragma unroll
                for (int qq = 0; qq < 4; ++qq) tv = fmaf(ov[qq], fws[(li8 * 4 + qq) * NC + cc], tv);
                lg[cc] = tv;
            }
#pragma unroll
            for (int m = 1; m <= 4; m <<= 1) {
#pragma unroll
                for (int cc = 0; cc < NC; ++cc) lg[cc] += __shfl_xor(lg[cc], m);
            }
#pragma unroll
            for (int cc = 0; cc < NC; ++cc) lg[cc] += fbs[cc];

            float mx = lg[0];
#pragma unroll
            for (int cc = 1; cc < NC; ++cc) mx = fmaxf(mx, lg[cc]);
            float ssum = 0.f;
#pragma unroll
            for (int cc = 0; cc < NC; ++cc) ssum += expf(lg[cc] - mx);
            float lse = mx + logf(ssum);

            float* orow = out + (size_t)n * NC;
            orow[li8] = lg[li8] - lse;
            if (li8 < 2) orow[8 + li8] = lg[8 + li8] - lse;
        }
    }
}

extern "C" void kernel_launch(void* const* d_in, const int* in_sizes, int n_in,
                              void* d_out, int out_size, void* d_ws, size_t ws_size,
                              hipStream_t stream) {
    const float* x    = (const float*)d_in[0];
    const float* ea   = (const float*)d_in[1];
    const int*   ei   = (const int*)d_in[2];
    const float* w1   = (const float*)d_in[3];
    const float* b1   = (const float*)d_in[4];
    const float* w2   = (const float*)d_in[5];
    const float* b2   = (const float*)d_in[6];
    const float* root = (const float*)d_in[7];
    const float* bias = (const float*)d_in[8];
    const float* fcw  = (const float*)d_in[9];
    const float* fcb  = (const float*)d_in[10];
    float* out = (float*)d_out;

    size_t off = 0;
    auto alloc = [&](size_t bytes) {
        void* p = (char*)d_ws + off;
        off += (bytes + 255) & ~(size_t)255;
        return p;
    };
    uint32_t* PQ       = (uint32_t*)alloc((size_t)NN * 32 * 4);                // 6.4 MB
    uint32_t* G2       = (uint32_t*)alloc((size_t)QG * 256 * 4);               // 2 MB (fallback)
    uint32_t* xh       = (uint32_t*)alloc((size_t)NN * INF_ * 2);              // 1.6 MB (fallback)
    uint16_t* H        = (uint16_t*)alloc((size_t)NB * NBLK * 2);              // 1.22 MB
    uint16_t* Bp       = (uint16_t*)alloc((size_t)NB * NBLK * 2);              // 1.22 MB
    uint32_t* tot      = (uint32_t*)alloc((size_t)NB * 4);
    uint32_t* bstart   = (uint32_t*)alloc((size_t)(NB + 1) * 4);
    uint2*    sorted   = (uint2*)alloc((size_t)NE * 8);                        // 6.4 MB

    prep_k<<<GB_PQ + GB_HIST + GB_G2 + GB_XH, 256, 0, stream>>>(
        w1, b1, w2, b2, x, ei, PQ, G2, xh, H);
    colsum_k<<<(NB * 64 + 255) / 256, 256, 0, stream>>>(H, Bp, tot);
    scatter_k<<<NBLK, 1024, 0, stream>>>(ei, ea, Bp, tot, bstart, sorted);
    fused_k<<<NB, 256, 0, stream>>>(sorted, bstart, w1, b1, x, PQ, xh, G2,
                                    root, bias, fcw, fcb, out);
}